// Round 11
// baseline (80.865 us; speedup 1.0000x reference)
//
#include <hip/hip_runtime.h>
#include <hip/hip_bf16.h>

typedef __attribute__((ext_vector_type(8))) short short8;
typedef __attribute__((ext_vector_type(4))) float f32x4;
typedef __attribute__((ext_vector_type(2))) float f32x2;

#define B_ 8
#define N_ 4096
#define E_ 16384
#define K_ 16
#define F_ 128

#if defined(__has_builtin)
#  if __has_builtin(__builtin_amdgcn_cvt_pk_f32_fp8) && __has_builtin(__builtin_amdgcn_cvt_pk_fp8_f32)
#    define HW_FP8 1
#  endif
#endif

__device__ __forceinline__ float bf2f(unsigned short h) {
    unsigned int u = ((unsigned int)h) << 16;
    union { unsigned int u; float f; } c; c.u = u; return c.f;
}
__device__ __forceinline__ unsigned short f2bf(float f) {
    union { float f; unsigned int u; } c; c.f = f;
    unsigned int u = c.u;
    unsigned int r = (u + 0x7fffu + ((u >> 16) & 1u)) >> 16;
    return (unsigned short)r;
}
__device__ __forceinline__ float fast_tanh(float x) {
    float e = __expf(2.0f * x);
    return 1.0f - 2.0f / (e + 1.0f);
}

// ---- fp8 e4m3fn helpers (HW cvt when available; exact manual fallback) ----
__device__ __forceinline__ unsigned int f2fp8_manual(float v) {
    unsigned int u = __float_as_uint(v * 0x1p-120f);
    unsigned int r = (u & 0x7fffffffu) + 0x7ffffu + ((u >> 20) & 1u);
    return ((r >> 20) & 0x7fu) | ((u >> 24) & 0x80u);
}
__device__ __forceinline__ unsigned int pack_fp8x4(float t0, float t1, float t2, float t3) {
#ifdef HW_FP8
    int wd = 0;
    wd = __builtin_amdgcn_cvt_pk_fp8_f32(t0, t1, wd, false);
    wd = __builtin_amdgcn_cvt_pk_fp8_f32(t2, t3, wd, true);
    return (unsigned int)wd;
#else
    return f2fp8_manual(t0) | (f2fp8_manual(t1) << 8) |
           (f2fp8_manual(t2) << 16) | (f2fp8_manual(t3) << 24);
#endif
}

// ---- detect whether an "integer" input buffer is int64 (high words all 0) ----
__device__ __forceinline__ int detect64(const int* raw) {
    int o = 0;
    #pragma unroll
    for (int i = 1; i < 128; i += 2) o |= raw[i];
    return (o == 0) ? 1 : 0;
}

// One launch, partitioned grid:
//   blocks [0,512):     sender[i] = edges[b,e,0]        (handles i32/i64)
//   blocks [512,2560):  pne[i] = mask[i] ? ne[i] : -1   (handles i32/i64)
//   blocks [2560,2576): wf = W1,W2 in MFMA fragment order (bf16)
__global__ void prep_idx(const int* __restrict__ edges_raw,
                         const int* __restrict__ ne_raw,
                         const int* __restrict__ mask,
                         const float* __restrict__ W1, const float* __restrict__ W2,
                         int* __restrict__ sender, int* __restrict__ pne,
                         unsigned short* __restrict__ wf) {
    int blk = blockIdx.x, tid = threadIdx.x;
    if (blk < 512) {
        __shared__ int s64;
        if (tid == 0) s64 = detect64(edges_raw);
        __syncthreads();
        int i = blk * 256 + tid;
        if (i < B_ * E_)
            sender[i] = s64 ? edges_raw[6 * (long long)i] : edges_raw[3 * (long long)i];
    } else if (blk < 2560) {
        __shared__ int s64;
        if (tid == 0) s64 = detect64(ne_raw);
        __syncthreads();
        int i = (blk - 512) * 256 + tid;
        if (i < B_ * N_ * K_) {
            int eid = s64 ? ne_raw[2 * (long long)i] : ne_raw[i];
            pne[i] = mask[i] ? eid : -1;
        }
    } else {
        int gtid = (blk - 2560) * 256 + tid;   // 0..4095
        int wsel = gtid >> 11;
        int q = gtid & 2047;
        int lane = q & 63;
        int gq = q >> 6;
        int nt = gq >> 2, g = gq & 3;
        const float* W = wsel ? W2 : W1;
        int j = nt * 16 + (lane & 15);
        int kbase = g * 32 + 8 * (lane >> 4);
        unsigned short* d = wf + wsel * 16384 + q * 8;
        #pragma unroll
        for (int t = 0; t < 8; ++t) d[t] = f2bf(W[j * 128 + kbase + t]);
    }
}

// edge_emb[b,e,:] = fp8( tanh( x[b,sender(e),:] @ W^T + bias ) )
// 64 edges/block, 4 waves. A=W (from wf), B=x^T -> D[j][edge];
// XCD-swizzled blocks: XCD x processes only batch x.
template <int SRC32>
__global__ void __launch_bounds__(256) edge_kernel(
    const void* __restrict__ xsrc, const int* __restrict__ sender,
    const unsigned short* __restrict__ wf, const float* __restrict__ bias,
    unsigned char* __restrict__ eout) {
    __shared__ short xt[64 * F_];   // 16 KB, chunk-swizzled
    __shared__ int sids[64];
    int tid = threadIdx.x;
    int swz = (blockIdx.x & 7) * 256 + (blockIdx.x >> 3);   // batch-per-XCD
    int b = swz >> 8;
    int e0 = (swz & 255) * 64;
    if (tid < 64) sids[tid] = sender[b * E_ + e0 + tid];
    __syncthreads();
    // stage 64 rows into LDS as bf16; 16B chunks, pch = ch ^ (row&15)
    #pragma unroll
    for (int c = 0; c < 4; ++c) {
        int ci = tid + 256 * c;         // 0..1023
        int row = ci >> 4, ch = ci & 15;
        int pch = ch ^ (row & 15);
        if (SRC32) {
            const float* src = (const float*)xsrc + ((long long)(b * N_ + sids[row])) * F_ + ch * 8;
            float4 v0 = *(const float4*)src;
            float4 v1 = *(const float4*)(src + 4);
            ushort4 h0, h1;
            h0.x = f2bf(v0.x); h0.y = f2bf(v0.y); h0.z = f2bf(v0.z); h0.w = f2bf(v0.w);
            h1.x = f2bf(v1.x); h1.y = f2bf(v1.y); h1.z = f2bf(v1.z); h1.w = f2bf(v1.w);
            *(ushort4*)&xt[row * F_ + pch * 8] = h0;
            *(ushort4*)&xt[row * F_ + pch * 8 + 4] = h1;
        } else {
            const int4* src = (const int4*)((const unsigned short*)xsrc +
                                ((long long)(b * N_ + sids[row])) * F_ + ch * 8);
            *(int4*)&xt[row * F_ + pch * 8] = *src;
        }
    }
    __syncthreads();
    int w = tid >> 6, lane = tid & 63;
    int erow = w * 16 + (lane & 15);      // this wave's 16 edges
    short8 bfr[4];
    #pragma unroll
    for (int g = 0; g < 4; ++g) {
        int pch = (g * 4 + (lane >> 4)) ^ (erow & 15);
        bfr[g] = *(const short8*)&xt[erow * F_ + pch * 8];
    }
    int jq = (lane >> 4) * 4;             // j sub-offset of this lane's 4 regs
    long long ebyte = ((long long)(b * E_ + e0 + w * 16 + (lane & 15))) * F_;  // fp8 row = 128B
    #pragma unroll
    for (int nt = 0; nt < 8; ++nt) {
        f32x4 acc = (f32x4){0.f, 0.f, 0.f, 0.f};
        #pragma unroll
        for (int g = 0; g < 4; ++g) {
            short8 afr = *(const short8*)(wf + ((nt * 4 + g) * 64 + lane) * 8);
            acc = __builtin_amdgcn_mfma_f32_16x16x32_bf16(afr, bfr[g], acc, 0, 0, 0);
        }
        float4 bv = *(const float4*)(bias + nt * 16 + jq);
        float t0 = fast_tanh(acc[0] + bv.x);
        float t1 = fast_tanh(acc[1] + bv.y);
        float t2 = fast_tanh(acc[2] + bv.z);
        float t3 = fast_tanh(acc[3] + bv.w);
        *(unsigned int*)(eout + ebyte + nt * 16 + jq) = pack_fp8x4(t0, t1, t2, t3);
    }
}

// x_next[b,n,:] = sum_k mask * edge_emb[b, ne[n,k], :] / (cnt + eps)
// ONE node per 8-lane octet (8 nodes/wave, 32/block): each lane owns 16
// fp8 cols = ONE 16B uint4 gather per k -> 16 independent 16B gathers in
// flight, no cross-lane reduce, half the gather instructions per node of
// the 16-lane variant. Index int4s broadcast across the octet via L1.
// XCD-swizzled: XCD x processes only batch x -> ebuf gathers L2-local.
__global__ void __launch_bounds__(256) agg_kernel(
    const unsigned char* __restrict__ ee, const int* __restrict__ pne,
    const float* __restrict__ x0, float* __restrict__ out,
    unsigned short* __restrict__ xbn, int col_off) {
    int tid = threadIdx.x;
    int swz = (blockIdx.x & 7) * 128 + (blockIdx.x >> 3);   // batch-per-XCD (1024 blocks)
    int nodeblk = swz * 32;            // 32 nodes per block
    int wid = tid >> 6, lane = tid & 63;
    int o8 = lane & 7;                 // col group: cols [o8*16, o8*16+16)
    int node = nodeblk + wid * 8 + (lane >> 3);
    int b = nodeblk >> 12;             // N=4096
    if (x0) {                          // copy 32 x0 rows -> out cols 0:128
        long long flat = (long long)nodeblk * F_ + tid * 16;
        int nn = tid >> 3;             // tid*16 / 128
        int j = (tid * 16) & 127;
        f32x4 c0 = *(const f32x4*)(x0 + flat);
        f32x4 c1 = *(const f32x4*)(x0 + flat + 4);
        f32x4 c2 = *(const f32x4*)(x0 + flat + 8);
        f32x4 c3 = *(const f32x4*)(x0 + flat + 12);
        float* od = out + (long long)(nodeblk + nn) * 384 + j;
        *(f32x4*)od = c0;
        *(f32x4*)(od + 4) = c1;
        *(f32x4*)(od + 8) = c2;
        *(f32x4*)(od + 12) = c3;
    }
    const int4* ip = (const int4*)(pne + node * K_);
    int4 i0 = ip[0], i1 = ip[1], i2 = ip[2], i3 = ip[3];
    float cnt = (float)((i0.x >= 0) + (i0.y >= 0) + (i0.z >= 0) + (i0.w >= 0) +
                        (i1.x >= 0) + (i1.y >= 0) + (i1.z >= 0) + (i1.w >= 0) +
                        (i2.x >= 0) + (i2.y >= 0) + (i2.z >= 0) + (i2.w >= 0) +
                        (i3.x >= 0) + (i3.y >= 0) + (i3.z >= 0) + (i3.w >= 0));
    const unsigned char* ebase = ee + (long long)b * (E_ * F_) + o8 * 16;
    float a0 = 0.f, a1 = 0.f, a2 = 0.f, a3 = 0.f;
    float a4 = 0.f, a5 = 0.f, a6 = 0.f, a7 = 0.f;
    float a8 = 0.f, a9 = 0.f, a10 = 0.f, a11 = 0.f;
    float a12 = 0.f, a13 = 0.f, a14 = 0.f, a15 = 0.f;
#ifdef HW_FP8
    #define PROC(pk) { \
        float m = ((pk) >= 0) ? 1.0f : 0.0f; \
        int eid = (pk) < 0 ? 0 : (pk); \
        uint4 v = *(const uint4*)(ebase + (long long)eid * F_); \
        f32x2 c; \
        c = __builtin_amdgcn_cvt_pk_f32_fp8(v.x, false); a0  += m * c.x; a1  += m * c.y; \
        c = __builtin_amdgcn_cvt_pk_f32_fp8(v.x, true);  a2  += m * c.x; a3  += m * c.y; \
        c = __builtin_amdgcn_cvt_pk_f32_fp8(v.y, false); a4  += m * c.x; a5  += m * c.y; \
        c = __builtin_amdgcn_cvt_pk_f32_fp8(v.y, true);  a6  += m * c.x; a7  += m * c.y; \
        c = __builtin_amdgcn_cvt_pk_f32_fp8(v.z, false); a8  += m * c.x; a9  += m * c.y; \
        c = __builtin_amdgcn_cvt_pk_f32_fp8(v.z, true);  a10 += m * c.x; a11 += m * c.y; \
        c = __builtin_amdgcn_cvt_pk_f32_fp8(v.w, false); a12 += m * c.x; a13 += m * c.y; \
        c = __builtin_amdgcn_cvt_pk_f32_fp8(v.w, true);  a14 += m * c.x; a15 += m * c.y; }
#else
    #define DEC(bb) __int_as_float((int)((((bb) & 0x80u) << 24) | (((bb) & 0x7fu) << 20)))
    #define PROC(pk) { \
        float ms = ((pk) >= 0) ? 0x1p120f : 0.0f; \
        int eid = (pk) < 0 ? 0 : (pk); \
        uint4 v = *(const uint4*)(ebase + (long long)eid * F_); \
        a0  += ms * DEC(v.x); a1  += ms * DEC(v.x >> 8); \
        a2  += ms * DEC(v.x >> 16); a3  += ms * DEC(v.x >> 24); \
        a4  += ms * DEC(v.y); a5  += ms * DEC(v.y >> 8); \
        a6  += ms * DEC(v.y >> 16); a7  += ms * DEC(v.y >> 24); \
        a8  += ms * DEC(v.z); a9  += ms * DEC(v.z >> 8); \
        a10 += ms * DEC(v.z >> 16); a11 += ms * DEC(v.z >> 24); \
        a12 += ms * DEC(v.w); a13 += ms * DEC(v.w >> 8); \
        a14 += ms * DEC(v.w >> 16); a15 += ms * DEC(v.w >> 24); }
#endif
    PROC(i0.x) PROC(i0.y) PROC(i0.z) PROC(i0.w)
    PROC(i1.x) PROC(i1.y) PROC(i1.z) PROC(i1.w)
    PROC(i2.x) PROC(i2.y) PROC(i2.z) PROC(i2.w)
    PROC(i3.x) PROC(i3.y) PROC(i3.z) PROC(i3.w)
    #undef PROC
    float inv = 1.0f / (cnt + 1e-8f);
    a0 *= inv; a1 *= inv; a2 *= inv; a3 *= inv;
    a4 *= inv; a5 *= inv; a6 *= inv; a7 *= inv;
    a8 *= inv; a9 *= inv; a10 *= inv; a11 *= inv;
    a12 *= inv; a13 *= inv; a14 *= inv; a15 *= inv;
    float* po = out + (long long)node * 384 + col_off + o8 * 16;
    *(f32x4*)po = (f32x4){a0, a1, a2, a3};
    *(f32x4*)(po + 4) = (f32x4){a4, a5, a6, a7};
    *(f32x4*)(po + 8) = (f32x4){a8, a9, a10, a11};
    *(f32x4*)(po + 12) = (f32x4){a12, a13, a14, a15};
    if (xbn) {
        unsigned short* ph = xbn + (long long)node * F_ + o8 * 16;
        short8 h0, h1;
        h0[0] = (short)f2bf(a0);  h0[1] = (short)f2bf(a1);
        h0[2] = (short)f2bf(a2);  h0[3] = (short)f2bf(a3);
        h0[4] = (short)f2bf(a4);  h0[5] = (short)f2bf(a5);
        h0[6] = (short)f2bf(a6);  h0[7] = (short)f2bf(a7);
        h1[0] = (short)f2bf(a8);  h1[1] = (short)f2bf(a9);
        h1[2] = (short)f2bf(a10); h1[3] = (short)f2bf(a11);
        h1[4] = (short)f2bf(a12); h1[5] = (short)f2bf(a13);
        h1[6] = (short)f2bf(a14); h1[7] = (short)f2bf(a15);
        *(short8*)ph = h0;
        *(short8*)(ph + 8) = h1;
    }
}

extern "C" void kernel_launch(void* const* d_in, const int* in_sizes, int n_in,
                              void* d_out, int out_size, void* d_ws, size_t ws_size,
                              hipStream_t stream) {
    const float* x0        = (const float*)d_in[0];
    const int*   edges_raw = (const int*)d_in[1];
    const int*   ne_raw    = (const int*)d_in[2];
    const int*   mask      = (const int*)d_in[3];
    const float* W1        = (const float*)d_in[4];
    const float* b1        = (const float*)d_in[5];
    const float* W2        = (const float*)d_in[6];
    const float* b2        = (const float*)d_in[7];
    float* out = (float*)d_out;
    char* ws = (char*)d_ws;

    unsigned char*  ebuf = (unsigned char*)ws;                    // B*E*F fp8  = 16 MB
    unsigned short* x1b  = (unsigned short*)(ws + 16777216);      // B*N*F bf16 = 8 MB
    unsigned short* wf   = (unsigned short*)(ws + 25165824);      // 2*128*128  = 64 KB
    int* sender32        = (int*)(ws + 25231360);                 // B*E int32  = 512 KB
    int* pne             = (int*)(ws + 25755648);                 // B*N*K      = 2 MB

    prep_idx<<<2576, 256, 0, stream>>>(edges_raw, ne_raw, mask, W1, W2,
                                       sender32, pne, wf);
    // round 1: edge transform from fp32 x0; agg also copies x0 -> out[:,0:128]
    edge_kernel<1><<<2048, 256, 0, stream>>>(x0, sender32, wf, b1, ebuf);
    agg_kernel<<<1024, 256, 0, stream>>>(ebuf, pne, x0, out, x1b, 128);
    // round 2
    edge_kernel<0><<<2048, 256, 0, stream>>>(x1b, sender32, wf + 16384, b2, ebuf);
    agg_kernel<<<1024, 256, 0, stream>>>(ebuf, pne, nullptr, out, nullptr, 256);
}

// Round 12
// 77.049 us; speedup vs baseline: 1.0495x; 1.0495x over previous
//
#include <hip/hip_runtime.h>
#include <hip/hip_bf16.h>

typedef __attribute__((ext_vector_type(8))) short short8;
typedef __attribute__((ext_vector_type(4))) float f32x4;
typedef __attribute__((ext_vector_type(2))) float f32x2;

#define B_ 8
#define N_ 4096
#define E_ 16384
#define K_ 16
#define F_ 128

#if defined(__has_builtin)
#  if __has_builtin(__builtin_amdgcn_cvt_pk_f32_fp8) && __has_builtin(__builtin_amdgcn_cvt_pk_fp8_f32)
#    define HW_FP8 1
#  endif
#endif

__device__ __forceinline__ unsigned short f2bf(float f) {
    union { float f; unsigned int u; } c; c.f = f;
    unsigned int u = c.u;
    unsigned int r = (u + 0x7fffu + ((u >> 16) & 1u)) >> 16;
    return (unsigned short)r;
}
__device__ __forceinline__ float fast_tanh(float x) {
    float e = __expf(2.0f * x);
    return 1.0f - 2.0f / (e + 1.0f);
}

// ---- fp8 e4m3fn helpers (HW cvt when available; exact manual fallback) ----
__device__ __forceinline__ unsigned int f2fp8_manual(float v) {
    unsigned int u = __float_as_uint(v * 0x1p-120f);
    unsigned int r = (u & 0x7fffffffu) + 0x7ffffu + ((u >> 20) & 1u);
    return ((r >> 20) & 0x7fu) | ((u >> 24) & 0x80u);
}
__device__ __forceinline__ unsigned int pack_fp8x4(float t0, float t1, float t2, float t3) {
#ifdef HW_FP8
    int wd = 0;
    wd = __builtin_amdgcn_cvt_pk_fp8_f32(t0, t1, wd, false);
    wd = __builtin_amdgcn_cvt_pk_fp8_f32(t2, t3, wd, true);
    return (unsigned int)wd;
#else
    return f2fp8_manual(t0) | (f2fp8_manual(t1) << 8) |
           (f2fp8_manual(t2) << 16) | (f2fp8_manual(t3) << 24);
#endif
}

// ---- detect whether an "integer" input buffer is int64 (high words all 0) ----
__device__ __forceinline__ int detect64(const int* raw) {
    int o = 0;
    #pragma unroll
    for (int i = 1; i < 128; i += 2) o |= raw[i];
    return (o == 0) ? 1 : 0;
}

// 17 blocks: [0,16) build wf = W1,W2 in MFMA fragment order (bf16);
// block 16 computes the i64/i32 flags ONCE into ws.
//   wf[((nt*4+g)*64+l)*8+t] = W[nt*16+(l&15)][g*32+8*(l>>4)+t]
__global__ void wprep(const float* __restrict__ W1, const float* __restrict__ W2,
                      const int* __restrict__ edges_raw, const int* __restrict__ ne_raw,
                      unsigned short* __restrict__ wf, int* __restrict__ flags) {
    int blk = blockIdx.x, tid = threadIdx.x;
    if (blk == 16) {
        if (tid == 0) {
            flags[0] = detect64(edges_raw);
            flags[1] = detect64(ne_raw);
        }
        return;
    }
    int gtid = blk * 256 + tid;    // 0..4095
    int wsel = gtid >> 11;
    int q = gtid & 2047;
    int lane = q & 63;
    int gq = q >> 6;
    int nt = gq >> 2, g = gq & 3;
    const float* W = wsel ? W2 : W1;
    int j = nt * 16 + (lane & 15);
    int kbase = g * 32 + 8 * (lane >> 4);
    unsigned short* d = wf + wsel * 16384 + q * 8;
    #pragma unroll
    for (int t = 0; t < 8; ++t) d[t] = f2bf(W[j * 128 + kbase + t]);
}

// edge_emb[b,e,:] = fp8( tanh( x[b,sender(e),:] @ W^T + bias ) )
// 64 edges/block, 4 waves. A=W (from wf), B=x^T -> D[j][edge].
// x rows are fp32 with runtime row-stride rs (x0: rs=128; round 2: rows
// live in out[:,:,128:256], rs=384). Sender ids read directly from
// edges_raw (i64/i32 flag precomputed in ws). Batch-per-XCD swizzle.
__global__ void __launch_bounds__(256) edge_kernel(
    const float* __restrict__ xsrc, int rs, const int* __restrict__ edges_raw,
    const int* __restrict__ flags, const unsigned short* __restrict__ wf,
    const float* __restrict__ bias, unsigned char* __restrict__ eout) {
    __shared__ short xt[64 * F_];   // 16 KB, chunk-swizzled
    __shared__ int sids[64];
    int tid = threadIdx.x;
    int swz = (blockIdx.x & 7) * 256 + (blockIdx.x >> 3);   // batch-per-XCD
    int b = swz >> 8;
    int e0 = (swz & 255) * 64;
    int s64e = flags[0];
    if (tid < 64) {
        long long ei = (long long)(b * E_ + e0 + tid);
        sids[tid] = s64e ? edges_raw[6 * ei] : edges_raw[3 * ei];
    }
    __syncthreads();
    // stage 64 rows into LDS as bf16; 16B chunks, pch = ch ^ (row&15)
    #pragma unroll
    for (int c = 0; c < 4; ++c) {
        int ci = tid + 256 * c;         // 0..1023
        int row = ci >> 4, ch = ci & 15;
        int pch = ch ^ (row & 15);
        const float* src = xsrc + (long long)(b * N_ + sids[row]) * rs + ch * 8;
        float4 v0 = *(const float4*)src;
        float4 v1 = *(const float4*)(src + 4);
        ushort4 h0, h1;
        h0.x = f2bf(v0.x); h0.y = f2bf(v0.y); h0.z = f2bf(v0.z); h0.w = f2bf(v0.w);
        h1.x = f2bf(v1.x); h1.y = f2bf(v1.y); h1.z = f2bf(v1.z); h1.w = f2bf(v1.w);
        *(ushort4*)&xt[row * F_ + pch * 8] = h0;
        *(ushort4*)&xt[row * F_ + pch * 8 + 4] = h1;
    }
    __syncthreads();
    int w = tid >> 6, lane = tid & 63;
    int erow = w * 16 + (lane & 15);      // this wave's 16 edges
    short8 bfr[4];
    #pragma unroll
    for (int g = 0; g < 4; ++g) {
        int pch = (g * 4 + (lane >> 4)) ^ (erow & 15);
        bfr[g] = *(const short8*)&xt[erow * F_ + pch * 8];
    }
    int jq = (lane >> 4) * 4;             // j sub-offset of this lane's 4 regs
    long long ebyte = ((long long)(b * E_ + e0 + w * 16 + (lane & 15))) * F_;  // fp8 row = 128B
    #pragma unroll
    for (int nt = 0; nt < 8; ++nt) {
        f32x4 acc = (f32x4){0.f, 0.f, 0.f, 0.f};
        #pragma unroll
        for (int g = 0; g < 4; ++g) {
            short8 afr = *(const short8*)(wf + ((nt * 4 + g) * 64 + lane) * 8);
            acc = __builtin_amdgcn_mfma_f32_16x16x32_bf16(afr, bfr[g], acc, 0, 0, 0);
        }
        float4 bv = *(const float4*)(bias + nt * 16 + jq);
        float t0 = fast_tanh(acc[0] + bv.x);
        float t1 = fast_tanh(acc[1] + bv.y);
        float t2 = fast_tanh(acc[2] + bv.z);
        float t3 = fast_tanh(acc[3] + bv.w);
        *(unsigned int*)(eout + ebyte + nt * 16 + jq) = pack_fp8x4(t0, t1, t2, t3);
    }
}

// x_next[b,n,:] = sum_k mask * edge_emb[b, ne[n,k], :] / (cnt + eps)
// ONE node per 16-lane quarter (round-10 best structure): lane owns 8 cols
// (8B fp8) and loops all 16 ks -> 16 independent 8B gathers in flight, no
// cross-lane reduce. Indices read directly from ne_raw/mask (flag-gated,
// uniform across the quarter -> L1 broadcast). fp8 ebuf slice = 2 MB/batch
// -> L2-resident per XCD (batch-per-XCD swizzle).
__global__ void __launch_bounds__(256) agg_kernel(
    const unsigned char* __restrict__ ee, const int* __restrict__ ne_raw,
    const int* __restrict__ mask, const int* __restrict__ flags,
    const float* __restrict__ x0, float* __restrict__ out, int col_off) {
    int tid = threadIdx.x;
    int swz = (blockIdx.x & 7) * 256 + (blockIdx.x >> 3);   // batch-per-XCD
    int nodeblk = swz * 16;            // 16 nodes per block
    int wid = tid >> 6, lane = tid & 63;
    int qt = lane >> 4, s16 = lane & 15;
    int node = nodeblk + wid * 4 + qt;
    int b = node >> 12;                // N=4096
    int s64n = flags[1];
    if (x0) {                          // copy 16 x0 rows -> out cols 0:128
        long long flat = (long long)nodeblk * F_ + tid * 8;
        int nn = tid >> 4;             // tid*8 / 128
        int j = (tid * 8) & 127;
        f32x4 c0 = *(const f32x4*)(x0 + flat);
        f32x4 c1 = *(const f32x4*)(x0 + flat + 4);
        float* od = out + (long long)(nodeblk + nn) * 384 + j;
        *(f32x4*)od = c0;
        *(f32x4*)(od + 4) = c1;
    }
    // indices + mask, direct from inputs
    int pk[16];
    {
        int mm[16];
        {
            const int4* mp4 = (const int4*)(mask + (long long)node * K_);
            #pragma unroll
            for (int i = 0; i < 4; ++i) {
                int4 v = mp4[i];
                mm[4 * i] = v.x; mm[4 * i + 1] = v.y;
                mm[4 * i + 2] = v.z; mm[4 * i + 3] = v.w;
            }
        }
        int ne_[16];
        if (s64n) {
            const int4* np = (const int4*)(ne_raw + 2ll * node * K_);
            #pragma unroll
            for (int i = 0; i < 8; ++i) {
                int4 v = np[i];
                ne_[2 * i] = v.x; ne_[2 * i + 1] = v.z;
            }
        } else {
            const int4* np = (const int4*)(ne_raw + (long long)node * K_);
            #pragma unroll
            for (int i = 0; i < 4; ++i) {
                int4 v = np[i];
                ne_[4 * i] = v.x; ne_[4 * i + 1] = v.y;
                ne_[4 * i + 2] = v.z; ne_[4 * i + 3] = v.w;
            }
        }
        #pragma unroll
        for (int i = 0; i < 16; ++i) pk[i] = mm[i] ? ne_[i] : -1;
    }
    float cnt = 0.f;
    #pragma unroll
    for (int i = 0; i < 16; ++i) cnt += (pk[i] >= 0) ? 1.0f : 0.0f;
    const unsigned char* ebase = ee + (long long)b * (E_ * F_) + s16 * 8;
    float a0 = 0.f, a1 = 0.f, a2 = 0.f, a3 = 0.f;
    float a4 = 0.f, a5 = 0.f, a6 = 0.f, a7 = 0.f;
#ifdef HW_FP8
    #define PROC(pkv) { \
        float m = ((pkv) >= 0) ? 1.0f : 0.0f; \
        int eid = (pkv) < 0 ? 0 : (pkv); \
        uint2 v = *(const uint2*)(ebase + (long long)eid * F_); \
        f32x2 c0 = __builtin_amdgcn_cvt_pk_f32_fp8(v.x, false); \
        f32x2 c1 = __builtin_amdgcn_cvt_pk_f32_fp8(v.x, true); \
        f32x2 c2 = __builtin_amdgcn_cvt_pk_f32_fp8(v.y, false); \
        f32x2 c3 = __builtin_amdgcn_cvt_pk_f32_fp8(v.y, true); \
        a0 += m * c0.x; a1 += m * c0.y; a2 += m * c1.x; a3 += m * c1.y; \
        a4 += m * c2.x; a5 += m * c2.y; a6 += m * c3.x; a7 += m * c3.y; }
#else
    #define DEC(bb) __int_as_float((int)((((bb) & 0x80u) << 24) | (((bb) & 0x7fu) << 20)))
    #define PROC(pkv) { \
        float ms = ((pkv) >= 0) ? 0x1p120f : 0.0f; \
        int eid = (pkv) < 0 ? 0 : (pkv); \
        uint2 v = *(const uint2*)(ebase + (long long)eid * F_); \
        a0 += ms * DEC(v.x); a1 += ms * DEC(v.x >> 8); \
        a2 += ms * DEC(v.x >> 16); a3 += ms * DEC(v.x >> 24); \
        a4 += ms * DEC(v.y); a5 += ms * DEC(v.y >> 8); \
        a6 += ms * DEC(v.y >> 16); a7 += ms * DEC(v.y >> 24); }
#endif
    PROC(pk[0])  PROC(pk[1])  PROC(pk[2])  PROC(pk[3])
    PROC(pk[4])  PROC(pk[5])  PROC(pk[6])  PROC(pk[7])
    PROC(pk[8])  PROC(pk[9])  PROC(pk[10]) PROC(pk[11])
    PROC(pk[12]) PROC(pk[13]) PROC(pk[14]) PROC(pk[15])
    #undef PROC
    float inv = 1.0f / (cnt + 1e-8f);
    a0 *= inv; a1 *= inv; a2 *= inv; a3 *= inv;
    a4 *= inv; a5 *= inv; a6 *= inv; a7 *= inv;
    float* po = out + (long long)node * 384 + col_off + s16 * 8;
    *(f32x4*)po = (f32x4){a0, a1, a2, a3};
    *(f32x4*)(po + 4) = (f32x4){a4, a5, a6, a7};
}

extern "C" void kernel_launch(void* const* d_in, const int* in_sizes, int n_in,
                              void* d_out, int out_size, void* d_ws, size_t ws_size,
                              hipStream_t stream) {
    const float* x0        = (const float*)d_in[0];
    const int*   edges_raw = (const int*)d_in[1];
    const int*   ne_raw    = (const int*)d_in[2];
    const int*   mask      = (const int*)d_in[3];
    const float* W1        = (const float*)d_in[4];
    const float* b1        = (const float*)d_in[5];
    const float* W2        = (const float*)d_in[6];
    const float* b2        = (const float*)d_in[7];
    float* out = (float*)d_out;
    char* ws = (char*)d_ws;

    unsigned char*  ebuf = (unsigned char*)ws;                    // B*E*F fp8  = 16 MB
    unsigned short* wf   = (unsigned short*)(ws + 16777216);      // 2*128*128  = 64 KB
    int* flags           = (int*)(ws + 16842752);                 // 2 x int32

    wprep<<<17, 256, 0, stream>>>(W1, W2, edges_raw, ne_raw, wf, flags);
    // round 1: x rows from x0 (rs=128); agg also copies x0 -> out[:,0:128]
    edge_kernel<<<2048, 256, 0, stream>>>(x0, 128, edges_raw, flags, wf, b1, ebuf);
    agg_kernel<<<2048, 256, 0, stream>>>(ebuf, ne_raw, mask, flags, x0, out, 128);
    // round 2: x rows are out[:,:,128:256] (fp32, rs=384)
    edge_kernel<<<2048, 256, 0, stream>>>(out + 128, 384, edges_raw, flags, wf + 16384, b2, ebuf);
    agg_kernel<<<2048, 256, 0, stream>>>(ebuf, ne_raw, mask, flags, nullptr, out, 256);
}

// Round 13
// 76.639 us; speedup vs baseline: 1.0551x; 1.0053x over previous
//
#include <hip/hip_runtime.h>
#include <hip/hip_bf16.h>

typedef __attribute__((ext_vector_type(8))) short short8;
typedef __attribute__((ext_vector_type(4))) float f32x4;
typedef __attribute__((ext_vector_type(2))) float f32x2;

#define B_ 8
#define N_ 4096
#define E_ 16384
#define K_ 16
#define F_ 128

#if defined(__has_builtin)
#  if __has_builtin(__builtin_amdgcn_cvt_pk_f32_fp8) && __has_builtin(__builtin_amdgcn_cvt_pk_fp8_f32)
#    define HW_FP8 1
#  endif
#endif

__device__ __forceinline__ unsigned short f2bf(float f) {
    union { float f; unsigned int u; } c; c.f = f;
    unsigned int u = c.u;
    unsigned int r = (u + 0x7fffu + ((u >> 16) & 1u)) >> 16;
    return (unsigned short)r;
}
__device__ __forceinline__ float fast_tanh(float x) {
    float e = __expf(2.0f * x);
    return 1.0f - 2.0f / (e + 1.0f);
}

// ---- fp8 e4m3fn helpers (HW cvt when available; exact manual fallback) ----
__device__ __forceinline__ unsigned int f2fp8_manual(float v) {
    unsigned int u = __float_as_uint(v * 0x1p-120f);
    unsigned int r = (u & 0x7fffffffu) + 0x7ffffu + ((u >> 20) & 1u);
    return ((r >> 20) & 0x7fu) | ((u >> 24) & 0x80u);
}
__device__ __forceinline__ unsigned int pack_fp8x4(float t0, float t1, float t2, float t3) {
#ifdef HW_FP8
    int wd = 0;
    wd = __builtin_amdgcn_cvt_pk_fp8_f32(t0, t1, wd, false);
    wd = __builtin_amdgcn_cvt_pk_fp8_f32(t2, t3, wd, true);
    return (unsigned int)wd;
#else
    return f2fp8_manual(t0) | (f2fp8_manual(t1) << 8) |
           (f2fp8_manual(t2) << 16) | (f2fp8_manual(t3) << 24);
#endif
}

// ---- detect whether an "integer" input buffer is int64 (high words all 0) ----
__device__ __forceinline__ int detect64(const int* raw) {
    int o = 0;
    #pragma unroll
    for (int i = 1; i < 128; i += 2) o |= raw[i];
    return (o == 0) ? 1 : 0;
}

// One launch, partitioned grid:
//   blocks [0,2048):    pne[i] = mask[i] ? ne[i] : -1   (handles i32/i64)
//   blocks [2048,2064): wf = W1,W2 in MFMA fragment order (bf16)
//   block 2064:         flags[0] = i64-ness of edges_raw
__global__ void prep_idx(const int* __restrict__ edges_raw,
                         const int* __restrict__ ne_raw,
                         const int* __restrict__ mask,
                         const float* __restrict__ W1, const float* __restrict__ W2,
                         int* __restrict__ pne, unsigned short* __restrict__ wf,
                         int* __restrict__ flags) {
    int blk = blockIdx.x, tid = threadIdx.x;
    if (blk < 2048) {
        __shared__ int s64;
        if (tid == 0) s64 = detect64(ne_raw);
        __syncthreads();
        int i = blk * 256 + tid;
        if (i < B_ * N_ * K_) {
            int eid = s64 ? ne_raw[2 * (long long)i] : ne_raw[i];
            pne[i] = mask[i] ? eid : -1;
        }
    } else if (blk < 2064) {
        int gtid = (blk - 2048) * 256 + tid;   // 0..4095
        int wsel = gtid >> 11;
        int q = gtid & 2047;
        int lane = q & 63;
        int gq = q >> 6;
        int nt = gq >> 2, g = gq & 3;
        const float* W = wsel ? W2 : W1;
        int j = nt * 16 + (lane & 15);
        int kbase = g * 32 + 8 * (lane >> 4);
        unsigned short* d = wf + wsel * 16384 + q * 8;
        #pragma unroll
        for (int t = 0; t < 8; ++t) d[t] = f2bf(W[j * 128 + kbase + t]);
    } else {
        if (tid == 0) flags[0] = detect64(edges_raw);
    }
}

// edge_emb[b,e,:] = fp8( tanh( x[b,sender(e),:] @ W^T + bias ) )
// 64 edges/block, 4 waves. A=W (from wf), B=x^T -> D[j][edge].
// Sender ids read directly from edges_raw (flag precomputed).
// XCD-swizzled blocks: XCD x processes only batch x.
template <int SRC32>
__global__ void __launch_bounds__(256) edge_kernel(
    const void* __restrict__ xsrc, const int* __restrict__ edges_raw,
    const int* __restrict__ flags, const unsigned short* __restrict__ wf,
    const float* __restrict__ bias, unsigned char* __restrict__ eout) {
    __shared__ short xt[64 * F_];   // 16 KB, chunk-swizzled
    __shared__ int sids[64];
    int tid = threadIdx.x;
    int swz = (blockIdx.x & 7) * 256 + (blockIdx.x >> 3);   // batch-per-XCD
    int b = swz >> 8;
    int e0 = (swz & 255) * 64;
    int s64e = flags[0];
    if (tid < 64) {
        long long ei = (long long)(b * E_ + e0 + tid);
        sids[tid] = s64e ? edges_raw[6 * ei] : edges_raw[3 * ei];
    }
    __syncthreads();
    // stage 64 rows into LDS as bf16; 16B chunks, pch = ch ^ (row&15)
    #pragma unroll
    for (int c = 0; c < 4; ++c) {
        int ci = tid + 256 * c;         // 0..1023
        int row = ci >> 4, ch = ci & 15;
        int pch = ch ^ (row & 15);
        if (SRC32) {
            const float* src = (const float*)xsrc + ((long long)(b * N_ + sids[row])) * F_ + ch * 8;
            float4 v0 = *(const float4*)src;
            float4 v1 = *(const float4*)(src + 4);
            ushort4 h0, h1;
            h0.x = f2bf(v0.x); h0.y = f2bf(v0.y); h0.z = f2bf(v0.z); h0.w = f2bf(v0.w);
            h1.x = f2bf(v1.x); h1.y = f2bf(v1.y); h1.z = f2bf(v1.z); h1.w = f2bf(v1.w);
            *(ushort4*)&xt[row * F_ + pch * 8] = h0;
            *(ushort4*)&xt[row * F_ + pch * 8 + 4] = h1;
        } else {
            const int4* src = (const int4*)((const unsigned short*)xsrc +
                                ((long long)(b * N_ + sids[row])) * F_ + ch * 8);
            *(int4*)&xt[row * F_ + pch * 8] = *src;
        }
    }
    __syncthreads();
    int w = tid >> 6, lane = tid & 63;
    int erow = w * 16 + (lane & 15);      // this wave's 16 edges
    short8 bfr[4];
    #pragma unroll
    for (int g = 0; g < 4; ++g) {
        int pch = (g * 4 + (lane >> 4)) ^ (erow & 15);
        bfr[g] = *(const short8*)&xt[erow * F_ + pch * 8];
    }
    int jq = (lane >> 4) * 4;             // j sub-offset of this lane's 4 regs
    long long ebyte = ((long long)(b * E_ + e0 + w * 16 + (lane & 15))) * F_;  // fp8 row = 128B
    #pragma unroll
    for (int nt = 0; nt < 8; ++nt) {
        f32x4 acc = (f32x4){0.f, 0.f, 0.f, 0.f};
        #pragma unroll
        for (int g = 0; g < 4; ++g) {
            short8 afr = *(const short8*)(wf + ((nt * 4 + g) * 64 + lane) * 8);
            acc = __builtin_amdgcn_mfma_f32_16x16x32_bf16(afr, bfr[g], acc, 0, 0, 0);
        }
        float4 bv = *(const float4*)(bias + nt * 16 + jq);
        float t0 = fast_tanh(acc[0] + bv.x);
        float t1 = fast_tanh(acc[1] + bv.y);
        float t2 = fast_tanh(acc[2] + bv.z);
        float t3 = fast_tanh(acc[3] + bv.w);
        *(unsigned int*)(eout + ebyte + nt * 16 + jq) = pack_fp8x4(t0, t1, t2, t3);
    }
}

// x_next[b,n,:] = sum_k mask * edge_emb[b, ne[n,k], :] / (cnt + eps)
// ONE node per 16-lane quarter (round-10 best structure): lane owns 8 cols
// (8B fp8), loops all 16 ks -> 16 independent 8B gathers in flight, no
// cross-lane reduce. NT stores on `out` (write-once) keep the XCD's L2 for
// the ebuf/x gather working set. XCD-swizzled: batch-per-XCD.
__global__ void __launch_bounds__(256) agg_kernel(
    const unsigned char* __restrict__ ee, const int* __restrict__ pne,
    const float* __restrict__ x0, float* __restrict__ out,
    unsigned short* __restrict__ xbn, int col_off) {
    int tid = threadIdx.x;
    int swz = (blockIdx.x & 7) * 256 + (blockIdx.x >> 3);   // batch-per-XCD
    int nodeblk = swz * 16;            // 16 nodes per block
    int wid = tid >> 6, lane = tid & 63;
    int qt = lane >> 4, s16 = lane & 15;
    int node = nodeblk + wid * 4 + qt;
    int b = node >> 12;                // N=4096
    if (x0) {                          // copy 16 x0 rows -> out cols 0:128 (NT)
        long long flat = (long long)nodeblk * F_ + tid * 8;
        int nn = tid >> 4;             // tid*8 / 128
        int j = (tid * 8) & 127;
        f32x4 c0 = *(const f32x4*)(x0 + flat);
        f32x4 c1 = *(const f32x4*)(x0 + flat + 4);
        float* od = out + (long long)(nodeblk + nn) * 384 + j;
        __builtin_nontemporal_store(c0, (f32x4*)od);
        __builtin_nontemporal_store(c1, (f32x4*)(od + 4));
    }
    const int4* ip = (const int4*)(pne + node * K_);
    int4 i0 = ip[0], i1 = ip[1], i2 = ip[2], i3 = ip[3];
    float cnt = (float)((i0.x >= 0) + (i0.y >= 0) + (i0.z >= 0) + (i0.w >= 0) +
                        (i1.x >= 0) + (i1.y >= 0) + (i1.z >= 0) + (i1.w >= 0) +
                        (i2.x >= 0) + (i2.y >= 0) + (i2.z >= 0) + (i2.w >= 0) +
                        (i3.x >= 0) + (i3.y >= 0) + (i3.z >= 0) + (i3.w >= 0));
    const unsigned char* ebase = ee + (long long)b * (E_ * F_) + s16 * 8;
    float a0 = 0.f, a1 = 0.f, a2 = 0.f, a3 = 0.f;
    float a4 = 0.f, a5 = 0.f, a6 = 0.f, a7 = 0.f;
#ifdef HW_FP8
    #define PROC(pk) { \
        float m = ((pk) >= 0) ? 1.0f : 0.0f; \
        int eid = (pk) < 0 ? 0 : (pk); \
        uint2 v = *(const uint2*)(ebase + (long long)eid * F_); \
        f32x2 c0 = __builtin_amdgcn_cvt_pk_f32_fp8(v.x, false); \
        f32x2 c1 = __builtin_amdgcn_cvt_pk_f32_fp8(v.x, true); \
        f32x2 c2 = __builtin_amdgcn_cvt_pk_f32_fp8(v.y, false); \
        f32x2 c3 = __builtin_amdgcn_cvt_pk_f32_fp8(v.y, true); \
        a0 += m * c0.x; a1 += m * c0.y; a2 += m * c1.x; a3 += m * c1.y; \
        a4 += m * c2.x; a5 += m * c2.y; a6 += m * c3.x; a7 += m * c3.y; }
#else
    #define DEC(bb) __int_as_float((int)((((bb) & 0x80u) << 24) | (((bb) & 0x7fu) << 20)))
    #define PROC(pk) { \
        float ms = ((pk) >= 0) ? 0x1p120f : 0.0f; \
        int eid = (pk) < 0 ? 0 : (pk); \
        uint2 v = *(const uint2*)(ebase + (long long)eid * F_); \
        a0 += ms * DEC(v.x); a1 += ms * DEC(v.x >> 8); \
        a2 += ms * DEC(v.x >> 16); a3 += ms * DEC(v.x >> 24); \
        a4 += ms * DEC(v.y); a5 += ms * DEC(v.y >> 8); \
        a6 += ms * DEC(v.y >> 16); a7 += ms * DEC(v.y >> 24); }
#endif
    PROC(i0.x) PROC(i0.y) PROC(i0.z) PROC(i0.w)
    PROC(i1.x) PROC(i1.y) PROC(i1.z) PROC(i1.w)
    PROC(i2.x) PROC(i2.y) PROC(i2.z) PROC(i2.w)
    PROC(i3.x) PROC(i3.y) PROC(i3.z) PROC(i3.w)
    #undef PROC
    float inv = 1.0f / (cnt + 1e-8f);
    a0 *= inv; a1 *= inv; a2 *= inv; a3 *= inv;
    a4 *= inv; a5 *= inv; a6 *= inv; a7 *= inv;
    float* po = out + (long long)node * 384 + col_off + s16 * 8;
    f32x4 o0 = (f32x4){a0, a1, a2, a3};
    f32x4 o1 = (f32x4){a4, a5, a6, a7};
    __builtin_nontemporal_store(o0, (f32x4*)po);
    __builtin_nontemporal_store(o1, (f32x4*)(po + 4));
    if (xbn) {
        short8 h;
        h[0] = (short)f2bf(a0); h[1] = (short)f2bf(a1);
        h[2] = (short)f2bf(a2); h[3] = (short)f2bf(a3);
        h[4] = (short)f2bf(a4); h[5] = (short)f2bf(a5);
        h[6] = (short)f2bf(a6); h[7] = (short)f2bf(a7);
        *(short8*)(xbn + (long long)node * F_ + s16 * 8) = h;
    }
}

extern "C" void kernel_launch(void* const* d_in, const int* in_sizes, int n_in,
                              void* d_out, int out_size, void* d_ws, size_t ws_size,
                              hipStream_t stream) {
    const float* x0        = (const float*)d_in[0];
    const int*   edges_raw = (const int*)d_in[1];
    const int*   ne_raw    = (const int*)d_in[2];
    const int*   mask      = (const int*)d_in[3];
    const float* W1        = (const float*)d_in[4];
    const float* b1        = (const float*)d_in[5];
    const float* W2        = (const float*)d_in[6];
    const float* b2        = (const float*)d_in[7];
    float* out = (float*)d_out;
    char* ws = (char*)d_ws;

    unsigned char*  ebuf = (unsigned char*)ws;                    // B*E*F fp8  = 16 MB
    unsigned short* x1b  = (unsigned short*)(ws + 16777216);      // B*N*F bf16 = 8 MB
    unsigned short* wf   = (unsigned short*)(ws + 25165824);      // 2*128*128  = 64 KB
    int* flags           = (int*)(ws + 25231360);                 // int32
    int* pne             = (int*)(ws + 25755648);                 // B*N*K      = 2 MB

    prep_idx<<<2065, 256, 0, stream>>>(edges_raw, ne_raw, mask, W1, W2,
                                       pne, wf, flags);
    // round 1: edge transform from fp32 x0; agg also copies x0 -> out[:,0:128]
    edge_kernel<1><<<2048, 256, 0, stream>>>(x0, edges_raw, flags, wf, b1, ebuf);
    agg_kernel<<<2048, 256, 0, stream>>>(ebuf, pne, x0, out, x1b, 128);
    // round 2
    edge_kernel<0><<<2048, 256, 0, stream>>>(x1b, edges_raw, flags, wf + 16384, b2, ebuf);
    agg_kernel<<<2048, 256, 0, stream>>>(ebuf, pne, nullptr, out, nullptr, 256);
}

// Round 14
// 75.489 us; speedup vs baseline: 1.0712x; 1.0152x over previous
//
#include <hip/hip_runtime.h>
#include <hip/hip_bf16.h>

typedef __attribute__((ext_vector_type(8))) short short8;
typedef __attribute__((ext_vector_type(4))) float f32x4;
typedef __attribute__((ext_vector_type(2))) float f32x2;

#define B_ 8
#define N_ 4096
#define E_ 16384
#define K_ 16
#define F_ 128

#if defined(__has_builtin)
#  if __has_builtin(__builtin_amdgcn_cvt_pk_f32_fp8) && __has_builtin(__builtin_amdgcn_cvt_pk_fp8_f32)
#    define HW_FP8 1
#  endif
#endif

__device__ __forceinline__ unsigned short f2bf(float f) {
    union { float f; unsigned int u; } c; c.f = f;
    unsigned int u = c.u;
    unsigned int r = (u + 0x7fffu + ((u >> 16) & 1u)) >> 16;
    return (unsigned short)r;
}
__device__ __forceinline__ float fast_tanh(float x) {
    float e = __expf(2.0f * x);
    return 1.0f - 2.0f / (e + 1.0f);
}

// ---- fp8 e4m3fn helpers (HW cvt when available; exact manual fallback) ----
__device__ __forceinline__ unsigned int f2fp8_manual(float v) {
    unsigned int u = __float_as_uint(v * 0x1p-120f);
    unsigned int r = (u & 0x7fffffffu) + 0x7ffffu + ((u >> 20) & 1u);
    return ((r >> 20) & 0x7fu) | ((u >> 24) & 0x80u);
}
__device__ __forceinline__ unsigned int pack_fp8x4(float t0, float t1, float t2, float t3) {
#ifdef HW_FP8
    int wd = 0;
    wd = __builtin_amdgcn_cvt_pk_fp8_f32(t0, t1, wd, false);
    wd = __builtin_amdgcn_cvt_pk_fp8_f32(t2, t3, wd, true);
    return (unsigned int)wd;
#else
    return f2fp8_manual(t0) | (f2fp8_manual(t1) << 8) |
           (f2fp8_manual(t2) << 16) | (f2fp8_manual(t3) << 24);
#endif
}

// ---- detect whether an "integer" input buffer is int64 (high words all 0) ----
__device__ __forceinline__ int detect64(const int* raw) {
    int o = 0;
    #pragma unroll
    for (int i = 1; i < 128; i += 2) o |= raw[i];
    return (o == 0) ? 1 : 0;
}

// 17 blocks: [0,16) build wf = W1,W2 in MFMA fragment order (bf16);
// block 16 computes the two i64/i32 flags ONCE.
//   wf[((nt*4+g)*64+l)*8+t] = W[nt*16+(l&15)][g*32+8*(l>>4)+t]
__global__ void wprep(const float* __restrict__ W1, const float* __restrict__ W2,
                      const int* __restrict__ edges_raw, const int* __restrict__ ne_raw,
                      unsigned short* __restrict__ wf, int* __restrict__ flags) {
    int blk = blockIdx.x, tid = threadIdx.x;
    if (blk == 16) {
        if (tid == 0) {
            flags[0] = detect64(edges_raw);
            flags[1] = detect64(ne_raw);
        }
        return;
    }
    int gtid = blk * 256 + tid;    // 0..4095
    int wsel = gtid >> 11;
    int q = gtid & 2047;
    int lane = q & 63;
    int gq = q >> 6;
    int nt = gq >> 2, g = gq & 3;
    const float* W = wsel ? W2 : W1;
    int j = nt * 16 + (lane & 15);
    int kbase = g * 32 + 8 * (lane >> 4);
    unsigned short* d = wf + wsel * 16384 + q * 8;
    #pragma unroll
    for (int t = 0; t < 8; ++t) d[t] = f2bf(W[j * 128 + kbase + t]);
}

// edge_emb[b,e,:] = fp8( tanh( x[b,sender(e),:] @ W^T + bias ) )
// 64 edges/block, 4 waves. A=W (from wf), B=x^T -> D[j][edge].
// Sender ids read directly from edges_raw (flag precomputed).
// DO_PNE: this launch also packs pne[i] = mask[i] ? ne[i] : -1, one entry
// per thread (2048 blocks x 256 threads == B*N*K) -- absorbed into edge1,
// consumed by the later agg launches. XCD-swizzled: batch-per-XCD.
template <int SRC32, int DO_PNE>
__global__ void __launch_bounds__(256) edge_kernel(
    const void* __restrict__ xsrc, const int* __restrict__ edges_raw,
    const int* __restrict__ ne_raw, const int* __restrict__ mask,
    const int* __restrict__ flags, const unsigned short* __restrict__ wf,
    const float* __restrict__ bias, unsigned char* __restrict__ eout,
    int* __restrict__ pne) {
    __shared__ short xt[64 * F_];   // 16 KB, chunk-swizzled
    __shared__ int sids[64];
    int tid = threadIdx.x;
    int swz = (blockIdx.x & 7) * 256 + (blockIdx.x >> 3);   // batch-per-XCD
    int b = swz >> 8;
    int e0 = (swz & 255) * 64;
    int s64e = flags[0];
    if (tid < 64) {
        long long ei = (long long)(b * E_ + e0 + tid);
        sids[tid] = s64e ? edges_raw[6 * ei] : edges_raw[3 * ei];
    }
    if (DO_PNE) {                       // coalesced, independent side-task
        int i = blockIdx.x * 256 + tid; // covers B*N*K exactly
        int s64n = flags[1];
        int eid = s64n ? ne_raw[2 * (long long)i] : ne_raw[i];
        pne[i] = mask[i] ? eid : -1;
    }
    __syncthreads();
    // stage 64 rows into LDS as bf16; 16B chunks, pch = ch ^ (row&15)
    #pragma unroll
    for (int c = 0; c < 4; ++c) {
        int ci = tid + 256 * c;         // 0..1023
        int row = ci >> 4, ch = ci & 15;
        int pch = ch ^ (row & 15);
        if (SRC32) {
            const float* src = (const float*)xsrc + ((long long)(b * N_ + sids[row])) * F_ + ch * 8;
            float4 v0 = *(const float4*)src;
            float4 v1 = *(const float4*)(src + 4);
            ushort4 h0, h1;
            h0.x = f2bf(v0.x); h0.y = f2bf(v0.y); h0.z = f2bf(v0.z); h0.w = f2bf(v0.w);
            h1.x = f2bf(v1.x); h1.y = f2bf(v1.y); h1.z = f2bf(v1.z); h1.w = f2bf(v1.w);
            *(ushort4*)&xt[row * F_ + pch * 8] = h0;
            *(ushort4*)&xt[row * F_ + pch * 8 + 4] = h1;
        } else {
            const int4* src = (const int4*)((const unsigned short*)xsrc +
                                ((long long)(b * N_ + sids[row])) * F_ + ch * 8);
            *(int4*)&xt[row * F_ + pch * 8] = *src;
        }
    }
    __syncthreads();
    int w = tid >> 6, lane = tid & 63;
    int erow = w * 16 + (lane & 15);      // this wave's 16 edges
    short8 bfr[4];
    #pragma unroll
    for (int g = 0; g < 4; ++g) {
        int pch = (g * 4 + (lane >> 4)) ^ (erow & 15);
        bfr[g] = *(const short8*)&xt[erow * F_ + pch * 8];
    }
    int jq = (lane >> 4) * 4;             // j sub-offset of this lane's 4 regs
    long long ebyte = ((long long)(b * E_ + e0 + w * 16 + (lane & 15))) * F_;  // fp8 row = 128B
    #pragma unroll
    for (int nt = 0; nt < 8; ++nt) {
        f32x4 acc = (f32x4){0.f, 0.f, 0.f, 0.f};
        #pragma unroll
        for (int g = 0; g < 4; ++g) {
            short8 afr = *(const short8*)(wf + ((nt * 4 + g) * 64 + lane) * 8);
            acc = __builtin_amdgcn_mfma_f32_16x16x32_bf16(afr, bfr[g], acc, 0, 0, 0);
        }
        float4 bv = *(const float4*)(bias + nt * 16 + jq);
        float t0 = fast_tanh(acc[0] + bv.x);
        float t1 = fast_tanh(acc[1] + bv.y);
        float t2 = fast_tanh(acc[2] + bv.z);
        float t3 = fast_tanh(acc[3] + bv.w);
        *(unsigned int*)(eout + ebyte + nt * 16 + jq) = pack_fp8x4(t0, t1, t2, t3);
    }
}

// x_next[b,n,:] = sum_k mask * edge_emb[b, ne[n,k], :] / (cnt + eps)
// ONE node per 16-lane quarter (round-10 best structure): lane owns 8 cols
// (8B fp8), loops all 16 ks -> 16 independent 8B gathers in flight, no
// cross-lane reduce. fp8 ebuf slice = 2 MB/batch -> L2-resident per XCD.
__global__ void __launch_bounds__(256) agg_kernel(
    const unsigned char* __restrict__ ee, const int* __restrict__ pne,
    const float* __restrict__ x0, float* __restrict__ out,
    unsigned short* __restrict__ xbn, int col_off) {
    int tid = threadIdx.x;
    int swz = (blockIdx.x & 7) * 256 + (blockIdx.x >> 3);   // batch-per-XCD
    int nodeblk = swz * 16;            // 16 nodes per block
    int wid = tid >> 6, lane = tid & 63;
    int qt = lane >> 4, s16 = lane & 15;
    int node = nodeblk + wid * 4 + qt;
    int b = node >> 12;                // N=4096
    if (x0) {                          // copy 16 x0 rows -> out cols 0:128
        long long flat = (long long)nodeblk * F_ + tid * 8;
        int nn = tid >> 4;             // tid*8 / 128
        int j = (tid * 8) & 127;
        f32x4 c0 = *(const f32x4*)(x0 + flat);
        f32x4 c1 = *(const f32x4*)(x0 + flat + 4);
        float* od = out + (long long)(nodeblk + nn) * 384 + j;
        *(f32x4*)od = c0;
        *(f32x4*)(od + 4) = c1;
    }
    const int4* ip = (const int4*)(pne + node * K_);
    int4 i0 = ip[0], i1 = ip[1], i2 = ip[2], i3 = ip[3];
    float cnt = (float)((i0.x >= 0) + (i0.y >= 0) + (i0.z >= 0) + (i0.w >= 0) +
                        (i1.x >= 0) + (i1.y >= 0) + (i1.z >= 0) + (i1.w >= 0) +
                        (i2.x >= 0) + (i2.y >= 0) + (i2.z >= 0) + (i2.w >= 0) +
                        (i3.x >= 0) + (i3.y >= 0) + (i3.z >= 0) + (i3.w >= 0));
    const unsigned char* ebase = ee + (long long)b * (E_ * F_) + s16 * 8;
    float a0 = 0.f, a1 = 0.f, a2 = 0.f, a3 = 0.f;
    float a4 = 0.f, a5 = 0.f, a6 = 0.f, a7 = 0.f;
#ifdef HW_FP8
    #define PROC(pk) { \
        float m = ((pk) >= 0) ? 1.0f : 0.0f; \
        int eid = (pk) < 0 ? 0 : (pk); \
        uint2 v = *(const uint2*)(ebase + (long long)eid * F_); \
        f32x2 c0 = __builtin_amdgcn_cvt_pk_f32_fp8(v.x, false); \
        f32x2 c1 = __builtin_amdgcn_cvt_pk_f32_fp8(v.x, true); \
        f32x2 c2 = __builtin_amdgcn_cvt_pk_f32_fp8(v.y, false); \
        f32x2 c3 = __builtin_amdgcn_cvt_pk_f32_fp8(v.y, true); \
        a0 += m * c0.x; a1 += m * c0.y; a2 += m * c1.x; a3 += m * c1.y; \
        a4 += m * c2.x; a5 += m * c2.y; a6 += m * c3.x; a7 += m * c3.y; }
#else
    #define DEC(bb) __int_as_float((int)((((bb) & 0x80u) << 24) | (((bb) & 0x7fu) << 20)))
    #define PROC(pk) { \
        float ms = ((pk) >= 0) ? 0x1p120f : 0.0f; \
        int eid = (pk) < 0 ? 0 : (pk); \
        uint2 v = *(const uint2*)(ebase + (long long)eid * F_); \
        a0 += ms * DEC(v.x); a1 += ms * DEC(v.x >> 8); \
        a2 += ms * DEC(v.x >> 16); a3 += ms * DEC(v.x >> 24); \
        a4 += ms * DEC(v.y); a5 += ms * DEC(v.y >> 8); \
        a6 += ms * DEC(v.y >> 16); a7 += ms * DEC(v.y >> 24); }
#endif
    PROC(i0.x) PROC(i0.y) PROC(i0.z) PROC(i0.w)
    PROC(i1.x) PROC(i1.y) PROC(i1.z) PROC(i1.w)
    PROC(i2.x) PROC(i2.y) PROC(i2.z) PROC(i2.w)
    PROC(i3.x) PROC(i3.y) PROC(i3.z) PROC(i3.w)
    #undef PROC
    float inv = 1.0f / (cnt + 1e-8f);
    a0 *= inv; a1 *= inv; a2 *= inv; a3 *= inv;
    a4 *= inv; a5 *= inv; a6 *= inv; a7 *= inv;
    float* po = out + (long long)node * 384 + col_off + s16 * 8;
    *(f32x4*)po = (f32x4){a0, a1, a2, a3};
    *(f32x4*)(po + 4) = (f32x4){a4, a5, a6, a7};
    if (xbn) {
        short8 h;
        h[0] = (short)f2bf(a0); h[1] = (short)f2bf(a1);
        h[2] = (short)f2bf(a2); h[3] = (short)f2bf(a3);
        h[4] = (short)f2bf(a4); h[5] = (short)f2bf(a5);
        h[6] = (short)f2bf(a6); h[7] = (short)f2bf(a7);
        *(short8*)(xbn + (long long)node * F_ + s16 * 8) = h;
    }
}

extern "C" void kernel_launch(void* const* d_in, const int* in_sizes, int n_in,
                              void* d_out, int out_size, void* d_ws, size_t ws_size,
                              hipStream_t stream) {
    const float* x0        = (const float*)d_in[0];
    const int*   edges_raw = (const int*)d_in[1];
    const int*   ne_raw    = (const int*)d_in[2];
    const int*   mask      = (const int*)d_in[3];
    const float* W1        = (const float*)d_in[4];
    const float* b1        = (const float*)d_in[5];
    const float* W2        = (const float*)d_in[6];
    const float* b2        = (const float*)d_in[7];
    float* out = (float*)d_out;
    char* ws = (char*)d_ws;

    unsigned char*  ebuf = (unsigned char*)ws;                    // B*E*F fp8  = 16 MB
    unsigned short* x1b  = (unsigned short*)(ws + 16777216);      // B*N*F bf16 = 8 MB
    unsigned short* wf   = (unsigned short*)(ws + 25165824);      // 2*128*128  = 64 KB
    int* flags           = (int*)(ws + 25231360);                 // 2 x int32
    int* pne             = (int*)(ws + 25755648);                 // B*N*K      = 2 MB

    wprep<<<17, 256, 0, stream>>>(W1, W2, edges_raw, ne_raw, wf, flags);
    // round 1: edge transform from fp32 x0 (also packs pne);
    //          agg also copies x0 -> out[:,0:128]
    edge_kernel<1, 1><<<2048, 256, 0, stream>>>(x0, edges_raw, ne_raw, mask,
                                                flags, wf, b1, ebuf, pne);
    agg_kernel<<<2048, 256, 0, stream>>>(ebuf, pne, x0, out, x1b, 128);
    // round 2
    edge_kernel<0, 0><<<2048, 256, 0, stream>>>(x1b, edges_raw, ne_raw, mask,
                                                flags, wf + 16384, b2, ebuf, pne);
    agg_kernel<<<2048, 256, 0, stream>>>(ebuf, pne, nullptr, out, nullptr, 256);
}

// Round 15
// 75.046 us; speedup vs baseline: 1.0775x; 1.0059x over previous
//
#include <hip/hip_runtime.h>
#include <hip/hip_bf16.h>

typedef __attribute__((ext_vector_type(8))) short short8;
typedef __attribute__((ext_vector_type(4))) float f32x4;
typedef __attribute__((ext_vector_type(2))) float f32x2;

#define B_ 8
#define N_ 4096
#define E_ 16384
#define K_ 16
#define F_ 128
#define NBLK 2048

#if defined(__has_builtin)
#  if __has_builtin(__builtin_amdgcn_cvt_pk_f32_fp8) && __has_builtin(__builtin_amdgcn_cvt_pk_fp8_f32)
#    define HW_FP8 1
#  endif
#endif

__device__ __forceinline__ unsigned short f2bf(float f) {
    union { float f; unsigned int u; } c; c.f = f;
    unsigned int u = c.u;
    unsigned int r = (u + 0x7fffu + ((u >> 16) & 1u)) >> 16;
    return (unsigned short)r;
}
__device__ __forceinline__ float fast_tanh(float x) {
    float e = __expf(2.0f * x);
    return 1.0f - 2.0f / (e + 1.0f);
}

// ---- fp8 e4m3fn helpers (HW cvt when available; exact manual fallback) ----
__device__ __forceinline__ unsigned int f2fp8_manual(float v) {
    unsigned int u = __float_as_uint(v * 0x1p-120f);
    unsigned int r = (u & 0x7fffffffu) + 0x7ffffu + ((u >> 20) & 1u);
    return ((r >> 20) & 0x7fu) | ((u >> 24) & 0x80u);
}
__device__ __forceinline__ unsigned int pack_fp8x4(float t0, float t1, float t2, float t3) {
#ifdef HW_FP8
    int wd = 0;
    wd = __builtin_amdgcn_cvt_pk_fp8_f32(t0, t1, wd, false);
    wd = __builtin_amdgcn_cvt_pk_fp8_f32(t2, t3, wd, true);
    return (unsigned int)wd;
#else
    return f2fp8_manual(t0) | (f2fp8_manual(t1) << 8) |
           (f2fp8_manual(t2) << 16) | (f2fp8_manual(t3) << 24);
#endif
}

// ---- detect whether an "integer" input buffer is int64 (high words all 0) ----
__device__ __forceinline__ int detect64(const int* raw) {
    int o = 0;
    #pragma unroll
    for (int i = 1; i < 128; i += 2) o |= raw[i];
    return (o == 0) ? 1 : 0;
}

// 17 blocks: [0,16) build wf (W1,W2 in MFMA fragment order, bf16);
// block 16: i64/i32 flags + zero the 3 grid-barrier counters.
__global__ void wprep(const float* __restrict__ W1, const float* __restrict__ W2,
                      const int* __restrict__ edges_raw, const int* __restrict__ ne_raw,
                      unsigned short* __restrict__ wf, int* __restrict__ flags) {
    int blk = blockIdx.x, tid = threadIdx.x;
    if (blk == 16) {
        if (tid == 0) {
            flags[0] = detect64(edges_raw);
            flags[1] = detect64(ne_raw);
            flags[4] = 0; flags[5] = 0; flags[6] = 0;   // barrier counters
        }
        return;
    }
    int gtid = blk * 256 + tid;    // 0..4095
    int wsel = gtid >> 11;
    int q = gtid & 2047;
    int lane = q & 63;
    int gq = q >> 6;
    int nt = gq >> 2, g = gq & 3;
    const float* W = wsel ? W2 : W1;
    int j = nt * 16 + (lane & 15);
    int kbase = g * 32 + 8 * (lane >> 4);
    unsigned short* d = wf + wsel * 16384 + q * 8;
    #pragma unroll
    for (int t = 0; t < 8; ++t) d[t] = f2bf(W[j * 128 + kbase + t]);
}

// ---------------- shared phase bodies (used by mega + fallback) -------------

// edge phase: edge_emb[b,e,:] = fp8(tanh(x[b,sender(e),:] @ W^T + b))
// 64 edges/block, 4 waves; A=W, B=x^T. DO_PNE packs pne with swz-mapped
// index so each pne slice is written on the XCD that later reads it.
template <int SRC32, int DO_PNE>
__device__ __forceinline__ void edge_body(
    short* xt, int* sids,
    const void* __restrict__ xsrc, const int* __restrict__ edges_raw,
    const int* __restrict__ ne_raw, const int* __restrict__ mask,
    const int* __restrict__ flags, const unsigned short* __restrict__ wf,
    const float* __restrict__ bias, unsigned char* __restrict__ eout,
    int* __restrict__ pne) {
    int tid = threadIdx.x;
    int swz = (blockIdx.x & 7) * 256 + (blockIdx.x >> 3);   // batch-per-XCD
    int b = swz >> 8;
    int e0 = (swz & 255) * 64;
    int s64e = flags[0];
    if (tid < 64) {
        long long ei = (long long)(b * E_ + e0 + tid);
        sids[tid] = s64e ? edges_raw[6 * ei] : edges_raw[3 * ei];
    }
    if (DO_PNE) {                       // XCD-aligned pne packing side-task
        int i = swz * 256 + tid;        // batch(i) == blk&7 == this XCD
        int s64n = flags[1];
        int eid = s64n ? ne_raw[2 * (long long)i] : ne_raw[i];
        pne[i] = mask[i] ? eid : -1;
    }
    __syncthreads();
    // stage 64 rows into LDS as bf16; 16B chunks, pch = ch ^ (row&15)
    #pragma unroll
    for (int c = 0; c < 4; ++c) {
        int ci = tid + 256 * c;         // 0..1023
        int row = ci >> 4, ch = ci & 15;
        int pch = ch ^ (row & 15);
        if (SRC32) {
            const float* src = (const float*)xsrc + ((long long)(b * N_ + sids[row])) * F_ + ch * 8;
            float4 v0 = *(const float4*)src;
            float4 v1 = *(const float4*)(src + 4);
            ushort4 h0, h1;
            h0.x = f2bf(v0.x); h0.y = f2bf(v0.y); h0.z = f2bf(v0.z); h0.w = f2bf(v0.w);
            h1.x = f2bf(v1.x); h1.y = f2bf(v1.y); h1.z = f2bf(v1.z); h1.w = f2bf(v1.w);
            *(ushort4*)&xt[row * F_ + pch * 8] = h0;
            *(ushort4*)&xt[row * F_ + pch * 8 + 4] = h1;
        } else {
            const int4* src = (const int4*)((const unsigned short*)xsrc +
                                ((long long)(b * N_ + sids[row])) * F_ + ch * 8);
            *(int4*)&xt[row * F_ + pch * 8] = *src;
        }
    }
    __syncthreads();
    int w = tid >> 6, lane = tid & 63;
    int erow = w * 16 + (lane & 15);      // this wave's 16 edges
    short8 bfr[4];
    #pragma unroll
    for (int g = 0; g < 4; ++g) {
        int pch = (g * 4 + (lane >> 4)) ^ (erow & 15);
        bfr[g] = *(const short8*)&xt[erow * F_ + pch * 8];
    }
    int jq = (lane >> 4) * 4;             // j sub-offset of this lane's 4 regs
    long long ebyte = ((long long)(b * E_ + e0 + w * 16 + (lane & 15))) * F_;  // fp8 row = 128B
    #pragma unroll
    for (int nt = 0; nt < 8; ++nt) {
        f32x4 acc = (f32x4){0.f, 0.f, 0.f, 0.f};
        #pragma unroll
        for (int g = 0; g < 4; ++g) {
            short8 afr = *(const short8*)(wf + ((nt * 4 + g) * 64 + lane) * 8);
            acc = __builtin_amdgcn_mfma_f32_16x16x32_bf16(afr, bfr[g], acc, 0, 0, 0);
        }
        float4 bv = *(const float4*)(bias + nt * 16 + jq);
        float t0 = fast_tanh(acc[0] + bv.x);
        float t1 = fast_tanh(acc[1] + bv.y);
        float t2 = fast_tanh(acc[2] + bv.z);
        float t3 = fast_tanh(acc[3] + bv.w);
        *(unsigned int*)(eout + ebyte + nt * 16 + jq) = pack_fp8x4(t0, t1, t2, t3);
    }
}

// agg phase: one node per 16-lane quarter; lane owns 8 cols (8B fp8), loops
// all 16 ks -> 16 independent gathers in flight, no cross-lane reduce.
__device__ __forceinline__ void agg_body(
    const unsigned char* __restrict__ ee, const int* __restrict__ pne,
    const float* __restrict__ x0, float* __restrict__ out,
    unsigned short* __restrict__ xbn, int col_off) {
    int tid = threadIdx.x;
    int swz = (blockIdx.x & 7) * 256 + (blockIdx.x >> 3);   // batch-per-XCD
    int nodeblk = swz * 16;            // 16 nodes per block
    int wid = tid >> 6, lane = tid & 63;
    int qt = lane >> 4, s16 = lane & 15;
    int node = nodeblk + wid * 4 + qt;
    int b = node >> 12;                // N=4096
    if (x0) {                          // copy 16 x0 rows -> out cols 0:128
        long long flat = (long long)nodeblk * F_ + tid * 8;
        int nn = tid >> 4;             // tid*8 / 128
        int j = (tid * 8) & 127;
        f32x4 c0 = *(const f32x4*)(x0 + flat);
        f32x4 c1 = *(const f32x4*)(x0 + flat + 4);
        float* od = out + (long long)(nodeblk + nn) * 384 + j;
        *(f32x4*)od = c0;
        *(f32x4*)(od + 4) = c1;
    }
    const int4* ip = (const int4*)(pne + node * K_);
    int4 i0 = ip[0], i1 = ip[1], i2 = ip[2], i3 = ip[3];
    float cnt = (float)((i0.x >= 0) + (i0.y >= 0) + (i0.z >= 0) + (i0.w >= 0) +
                        (i1.x >= 0) + (i1.y >= 0) + (i1.z >= 0) + (i1.w >= 0) +
                        (i2.x >= 0) + (i2.y >= 0) + (i2.z >= 0) + (i2.w >= 0) +
                        (i3.x >= 0) + (i3.y >= 0) + (i3.z >= 0) + (i3.w >= 0));
    const unsigned char* ebase = ee + (long long)b * (E_ * F_) + s16 * 8;
    float a0 = 0.f, a1 = 0.f, a2 = 0.f, a3 = 0.f;
    float a4 = 0.f, a5 = 0.f, a6 = 0.f, a7 = 0.f;
#ifdef HW_FP8
    #define PROC(pk) { \
        float m = ((pk) >= 0) ? 1.0f : 0.0f; \
        int eid = (pk) < 0 ? 0 : (pk); \
        uint2 v = *(const uint2*)(ebase + (long long)eid * F_); \
        f32x2 c0 = __builtin_amdgcn_cvt_pk_f32_fp8(v.x, false); \
        f32x2 c1 = __builtin_amdgcn_cvt_pk_f32_fp8(v.x, true); \
        f32x2 c2 = __builtin_amdgcn_cvt_pk_f32_fp8(v.y, false); \
        f32x2 c3 = __builtin_amdgcn_cvt_pk_f32_fp8(v.y, true); \
        a0 += m * c0.x; a1 += m * c0.y; a2 += m * c1.x; a3 += m * c1.y; \
        a4 += m * c2.x; a5 += m * c2.y; a6 += m * c3.x; a7 += m * c3.y; }
#else
    #define DEC(bb) __int_as_float((int)((((bb) & 0x80u) << 24) | (((bb) & 0x7fu) << 20)))
    #define PROC(pk) { \
        float ms = ((pk) >= 0) ? 0x1p120f : 0.0f; \
        int eid = (pk) < 0 ? 0 : (pk); \
        uint2 v = *(const uint2*)(ebase + (long long)eid * F_); \
        a0 += ms * DEC(v.x); a1 += ms * DEC(v.x >> 8); \
        a2 += ms * DEC(v.x >> 16); a3 += ms * DEC(v.x >> 24); \
        a4 += ms * DEC(v.y); a5 += ms * DEC(v.y >> 8); \
        a6 += ms * DEC(v.y >> 16); a7 += ms * DEC(v.y >> 24); }
#endif
    PROC(i0.x) PROC(i0.y) PROC(i0.z) PROC(i0.w)
    PROC(i1.x) PROC(i1.y) PROC(i1.z) PROC(i1.w)
    PROC(i2.x) PROC(i2.y) PROC(i2.z) PROC(i2.w)
    PROC(i3.x) PROC(i3.y) PROC(i3.z) PROC(i3.w)
    #undef PROC
    float inv = 1.0f / (cnt + 1e-8f);
    a0 *= inv; a1 *= inv; a2 *= inv; a3 *= inv;
    a4 *= inv; a5 *= inv; a6 *= inv; a7 *= inv;
    float* po = out + (long long)node * 384 + col_off + s16 * 8;
    *(f32x4*)po = (f32x4){a0, a1, a2, a3};
    *(f32x4*)(po + 4) = (f32x4){a4, a5, a6, a7};
    if (xbn) {
        short8 h;
        h[0] = (short)f2bf(a0); h[1] = (short)f2bf(a1);
        h[2] = (short)f2bf(a2); h[3] = (short)f2bf(a3);
        h[4] = (short)f2bf(a4); h[5] = (short)f2bf(a5);
        h[6] = (short)f2bf(a6); h[7] = (short)f2bf(a7);
        *(short8*)(xbn + (long long)node * F_ + s16 * 8) = h;
    }
}

// ---------------- fallback kernels (r14-proven 5-launch path) ---------------

template <int SRC32, int DO_PNE>
__global__ void __launch_bounds__(256) edge_kernel(
    const void* xsrc, const int* edges_raw, const int* ne_raw, const int* mask,
    const int* flags, const unsigned short* wf, const float* bias,
    unsigned char* eout, int* pne) {
    __shared__ short xt[64 * F_];
    __shared__ int sids[64];
    edge_body<SRC32, DO_PNE>(xt, sids, xsrc, edges_raw, ne_raw, mask, flags,
                             wf, bias, eout, pne);
}

__global__ void __launch_bounds__(256) agg_kernel(
    const unsigned char* ee, const int* pne, const float* x0, float* out,
    unsigned short* xbn, int col_off) {
    agg_body(ee, pne, x0, out, xbn, col_off);
}

// ---------------- mega kernel: 4 phases, 3 grid barriers ---------------------
// All inter-phase buffers (ebuf, pne, x1b) are XCD-local by the batch-per-XCD
// swizzle, so no data fences are needed: __syncthreads drains each block's
// stores into its own XCD L2 before arrival; readers are on the same XCD.
// The counter itself uses device-scope relaxed atomics (coherent at L3).

__device__ __forceinline__ void grid_bar(int* cnt) {
    __syncthreads();
    if (threadIdx.x == 0) {
        __hip_atomic_fetch_add(cnt, 1, __ATOMIC_RELAXED, __HIP_MEMORY_SCOPE_AGENT);
        while (__hip_atomic_load(cnt, __ATOMIC_RELAXED, __HIP_MEMORY_SCOPE_AGENT) < NBLK) {
            __builtin_amdgcn_s_sleep(2);
        }
    }
    __syncthreads();
}

__global__ void __launch_bounds__(256, 8) mega_kernel(
    const float* __restrict__ x0, const int* __restrict__ edges_raw,
    const int* __restrict__ ne_raw, const int* __restrict__ mask,
    int* __restrict__ flags, const unsigned short* __restrict__ wf,
    const float* __restrict__ b1, const float* __restrict__ b2,
    unsigned char* __restrict__ ebuf, unsigned short* __restrict__ x1b,
    int* __restrict__ pne, float* __restrict__ out) {
    __shared__ short xt[64 * F_];
    __shared__ int sids[64];
    int* cnt = flags + 4;
    // phase 1: edge round 1 (fp32 x0 source) + pne packing
    edge_body<1, 1>(xt, sids, x0, edges_raw, ne_raw, mask, flags, wf, b1, ebuf, pne);
    grid_bar(cnt + 0);
    // phase 2: agg round 1 (+ x0 copy), writes x1b
    agg_body(ebuf, pne, x0, out, x1b, 128);
    grid_bar(cnt + 1);
    // phase 3: edge round 2 (bf16 x1b source)
    edge_body<0, 0>(xt, sids, x1b, edges_raw, ne_raw, mask, flags, wf + 16384, b2, ebuf, pne);
    grid_bar(cnt + 2);
    // phase 4: agg round 2
    agg_body(ebuf, pne, nullptr, out, nullptr, 256);
}

extern "C" void kernel_launch(void* const* d_in, const int* in_sizes, int n_in,
                              void* d_out, int out_size, void* d_ws, size_t ws_size,
                              hipStream_t stream) {
    const float* x0        = (const float*)d_in[0];
    const int*   edges_raw = (const int*)d_in[1];
    const int*   ne_raw    = (const int*)d_in[2];
    const int*   mask      = (const int*)d_in[3];
    const float* W1        = (const float*)d_in[4];
    const float* b1        = (const float*)d_in[5];
    const float* W2        = (const float*)d_in[6];
    const float* b2        = (const float*)d_in[7];
    float* out = (float*)d_out;
    char* ws = (char*)d_ws;

    unsigned char*  ebuf = (unsigned char*)ws;                    // B*E*F fp8  = 16 MB
    unsigned short* x1b  = (unsigned short*)(ws + 16777216);      // B*N*F bf16 = 8 MB
    unsigned short* wf   = (unsigned short*)(ws + 25165824);      // 2*128*128  = 64 KB
    int* flags           = (int*)(ws + 25231360);                 // flags[0..1], counters [4..6]
    int* pne             = (int*)(ws + 25755648);                 // B*N*K      = 2 MB

    wprep<<<17, 256, 0, stream>>>(W1, W2, edges_raw, ne_raw, wf, flags);

    // co-residency check for the spin-barrier mega kernel (deterministic)
    int nb = 0;
    (void)hipOccupancyMaxActiveBlocksPerMultiprocessor(&nb, (const void*)mega_kernel, 256, 0);
    if (nb >= 8) {
        mega_kernel<<<NBLK, 256, 0, stream>>>(x0, edges_raw, ne_raw, mask, flags,
                                              wf, b1, b2, ebuf, x1b, pne, out);
    } else {
        edge_kernel<1, 1><<<2048, 256, 0, stream>>>(x0, edges_raw, ne_raw, mask,
                                                    flags, wf, b1, ebuf, pne);
        agg_kernel<<<2048, 256, 0, stream>>>(ebuf, pne, x0, out, x1b, 128);
        edge_kernel<0, 0><<<2048, 256, 0, stream>>>(x1b, edges_raw, ne_raw, mask,
                                                    flags, wf + 16384, b2, ebuf, pne);
        agg_kernel<<<2048, 256, 0, stream>>>(ebuf, pne, nullptr, out, nullptr, 256);
    }
}

// Round 16
// 74.503 us; speedup vs baseline: 1.0854x; 1.0073x over previous
//
#include <hip/hip_runtime.h>
#include <hip/hip_bf16.h>

typedef __attribute__((ext_vector_type(8))) short short8;
typedef __attribute__((ext_vector_type(4))) float f32x4;
typedef __attribute__((ext_vector_type(2))) float f32x2;

#define B_ 8
#define N_ 4096
#define E_ 16384
#define K_ 16
#define F_ 128
#define NBLK 2048

#if defined(__has_builtin)
#  if __has_builtin(__builtin_amdgcn_cvt_pk_f32_fp8) && __has_builtin(__builtin_amdgcn_cvt_pk_fp8_f32)
#    define HW_FP8 1
#  endif
#endif

__device__ __forceinline__ unsigned short f2bf(float f) {
    union { float f; unsigned int u; } c; c.f = f;
    unsigned int u = c.u;
    unsigned int r = (u + 0x7fffu + ((u >> 16) & 1u)) >> 16;
    return (unsigned short)r;
}
__device__ __forceinline__ float fast_tanh(float x) {
    float e = __expf(2.0f * x);
    return 1.0f - 2.0f / (e + 1.0f);
}

// ---- fp8 e4m3 codec (HW when available; matched manual encode/decode pair) ----
__device__ __forceinline__ unsigned int f2fp8_manual(float v) {
    unsigned int u = __float_as_uint(v * 0x1p-120f);
    unsigned int r = (u & 0x7fffffffu) + 0x7ffffu + ((u >> 20) & 1u);
    return ((r >> 20) & 0x7fu) | ((u >> 24) & 0x80u);
}
__device__ __forceinline__ unsigned int pack_fp8x4(float t0, float t1, float t2, float t3) {
#ifdef HW_FP8
    int wd = 0;
    wd = __builtin_amdgcn_cvt_pk_fp8_f32(t0, t1, wd, false);
    wd = __builtin_amdgcn_cvt_pk_fp8_f32(t2, t3, wd, true);
    return (unsigned int)wd;
#else
    return f2fp8_manual(t0) | (f2fp8_manual(t1) << 8) |
           (f2fp8_manual(t2) << 16) | (f2fp8_manual(t3) << 24);
#endif
}
#ifndef HW_FP8
#define DECM(bb) __int_as_float((int)((((bb) & 0x80u) << 24) | (((bb) & 0x7fu) << 20)))
#endif

// ---- detect whether an "integer" input buffer is int64 (high words all 0) ----
__device__ __forceinline__ int detect64(const int* raw) {
    int o = 0;
    #pragma unroll
    for (int i = 1; i < 128; i += 2) o |= raw[i];
    return (o == 0) ? 1 : 0;
}

// 17 blocks: [0,16) build wf (W1,W2 in MFMA fragment order, bf16);
// block 16: i64/i32 flags + zero the per-XCD barrier counters (3 x 8).
__global__ void wprep(const float* __restrict__ W1, const float* __restrict__ W2,
                      const int* __restrict__ edges_raw, const int* __restrict__ ne_raw,
                      unsigned short* __restrict__ wf, int* __restrict__ flags) {
    int blk = blockIdx.x, tid = threadIdx.x;
    if (blk == 16) {
        if (tid == 0) {
            flags[0] = detect64(edges_raw);
            flags[1] = detect64(ne_raw);
        }
        if (tid < 24) flags[4 + tid] = 0;   // barrier counters [4..28)
        return;
    }
    int gtid = blk * 256 + tid;    // 0..4095
    int wsel = gtid >> 11;
    int q = gtid & 2047;
    int lane = q & 63;
    int gq = q >> 6;
    int nt = gq >> 2, g = gq & 3;
    const float* W = wsel ? W2 : W1;
    int j = nt * 16 + (lane & 15);
    int kbase = g * 32 + 8 * (lane >> 4);
    unsigned short* d = wf + wsel * 16384 + q * 8;
    #pragma unroll
    for (int t = 0; t < 8; ++t) d[t] = f2bf(W[j * 128 + kbase + t]);
}

// ---------------- shared phase bodies (used by mega + fallback) -------------

// edge phase: ebuf[b,e,:] = fp8(tanh(x[b,sender(e),:] @ W^T + b))
// SRC: 1 = fp32 rows (x0), 2 = fp8 rows (x1). 64 edges/block, 4 waves.
// DO_PNE packs pne with swz-mapped index (written on the consuming XCD).
template <int SRC, int DO_PNE>
__device__ __forceinline__ void edge_body(
    short* xt, int* sids,
    const void* __restrict__ xsrc, const int* __restrict__ edges_raw,
    const int* __restrict__ ne_raw, const int* __restrict__ mask,
    const int* __restrict__ flags, const unsigned short* __restrict__ wf,
    const float* __restrict__ bias, unsigned char* __restrict__ eout,
    int* __restrict__ pne) {
    int tid = threadIdx.x;
    int swz = (blockIdx.x & 7) * 256 + (blockIdx.x >> 3);   // batch-per-XCD
    int b = swz >> 8;
    int e0 = (swz & 255) * 64;
    int s64e = flags[0];
    if (tid < 64) {
        long long ei = (long long)(b * E_ + e0 + tid);
        sids[tid] = s64e ? edges_raw[6 * ei] : edges_raw[3 * ei];
    }
    if (DO_PNE) {                       // XCD-aligned pne packing side-task
        int i = swz * 256 + tid;        // batch(i) == blk&7 == this XCD
        int s64n = flags[1];
        int eid = s64n ? ne_raw[2 * (long long)i] : ne_raw[i];
        pne[i] = mask[i] ? eid : -1;
    }
    __syncthreads();
    // stage 64 rows into LDS as bf16; 16B chunks, pch = ch ^ (row&15)
    #pragma unroll
    for (int c = 0; c < 4; ++c) {
        int ci = tid + 256 * c;         // 0..1023
        int row = ci >> 4, ch = ci & 15;
        int pch = ch ^ (row & 15);
        if (SRC == 1) {
            const float* src = (const float*)xsrc + ((long long)(b * N_ + sids[row])) * F_ + ch * 8;
            float4 v0 = *(const float4*)src;
            float4 v1 = *(const float4*)(src + 4);
            ushort4 h0, h1;
            h0.x = f2bf(v0.x); h0.y = f2bf(v0.y); h0.z = f2bf(v0.z); h0.w = f2bf(v0.w);
            h1.x = f2bf(v1.x); h1.y = f2bf(v1.y); h1.z = f2bf(v1.z); h1.w = f2bf(v1.w);
            *(ushort4*)&xt[row * F_ + pch * 8] = h0;
            *(ushort4*)&xt[row * F_ + pch * 8 + 4] = h1;
        } else {
            // fp8 row: 8 bytes per chunk -> 8 bf16 (exact, e4m3 subset of bf16)
            const unsigned char* src = (const unsigned char*)xsrc +
                ((long long)(b * N_ + sids[row])) * F_ + ch * 8;
            uint2 v = *(const uint2*)src;
            short8 h;
#ifdef HW_FP8
            f32x2 c0 = __builtin_amdgcn_cvt_pk_f32_fp8(v.x, false);
            f32x2 c1 = __builtin_amdgcn_cvt_pk_f32_fp8(v.x, true);
            f32x2 c2 = __builtin_amdgcn_cvt_pk_f32_fp8(v.y, false);
            f32x2 c3 = __builtin_amdgcn_cvt_pk_f32_fp8(v.y, true);
            h[0] = (short)f2bf(c0.x); h[1] = (short)f2bf(c0.y);
            h[2] = (short)f2bf(c1.x); h[3] = (short)f2bf(c1.y);
            h[4] = (short)f2bf(c2.x); h[5] = (short)f2bf(c2.y);
            h[6] = (short)f2bf(c3.x); h[7] = (short)f2bf(c3.y);
#else
            h[0] = (short)f2bf(0x1p120f * DECM(v.x));
            h[1] = (short)f2bf(0x1p120f * DECM(v.x >> 8));
            h[2] = (short)f2bf(0x1p120f * DECM(v.x >> 16));
            h[3] = (short)f2bf(0x1p120f * DECM(v.x >> 24));
            h[4] = (short)f2bf(0x1p120f * DECM(v.y));
            h[5] = (short)f2bf(0x1p120f * DECM(v.y >> 8));
            h[6] = (short)f2bf(0x1p120f * DECM(v.y >> 16));
            h[7] = (short)f2bf(0x1p120f * DECM(v.y >> 24));
#endif
            *(short8*)&xt[row * F_ + pch * 8] = h;
        }
    }
    __syncthreads();
    int w = tid >> 6, lane = tid & 63;
    int erow = w * 16 + (lane & 15);      // this wave's 16 edges
    short8 bfr[4];
    #pragma unroll
    for (int g = 0; g < 4; ++g) {
        int pch = (g * 4 + (lane >> 4)) ^ (erow & 15);
        bfr[g] = *(const short8*)&xt[erow * F_ + pch * 8];
    }
    int jq = (lane >> 4) * 4;             // j sub-offset of this lane's 4 regs
    long long ebyte = ((long long)(b * E_ + e0 + w * 16 + (lane & 15))) * F_;  // fp8 row = 128B
    #pragma unroll
    for (int nt = 0; nt < 8; ++nt) {
        f32x4 acc = (f32x4){0.f, 0.f, 0.f, 0.f};
        #pragma unroll
        for (int g = 0; g < 4; ++g) {
            short8 afr = *(const short8*)(wf + ((nt * 4 + g) * 64 + lane) * 8);
            acc = __builtin_amdgcn_mfma_f32_16x16x32_bf16(afr, bfr[g], acc, 0, 0, 0);
        }
        float4 bv = *(const float4*)(bias + nt * 16 + jq);
        float t0 = fast_tanh(acc[0] + bv.x);
        float t1 = fast_tanh(acc[1] + bv.y);
        float t2 = fast_tanh(acc[2] + bv.z);
        float t3 = fast_tanh(acc[3] + bv.w);
        *(unsigned int*)(eout + ebyte + nt * 16 + jq) = pack_fp8x4(t0, t1, t2, t3);
    }
}

// agg phase: one node per 16-lane quarter; lane owns 8 cols (8B fp8), loops
// all 16 ks -> 16 independent gathers in flight, no cross-lane reduce.
// NT=1: nontemporal out stores (mega path: preserve L2 for gather set).
// xf8: optional fp8 x1 output (values in [-1,1]).
template <int NT>
__device__ __forceinline__ void agg_body(
    const unsigned char* __restrict__ ee, const int* __restrict__ pne,
    const float* __restrict__ x0, float* __restrict__ out,
    unsigned char* __restrict__ xf8, int col_off) {
    int tid = threadIdx.x;
    int swz = (blockIdx.x & 7) * 256 + (blockIdx.x >> 3);   // batch-per-XCD
    int nodeblk = swz * 16;            // 16 nodes per block
    int wid = tid >> 6, lane = tid & 63;
    int qt = lane >> 4, s16 = lane & 15;
    int node = nodeblk + wid * 4 + qt;
    int b = node >> 12;                // N=4096
    if (x0) {                          // copy 16 x0 rows -> out cols 0:128
        long long flat = (long long)nodeblk * F_ + tid * 8;
        int nn = tid >> 4;             // tid*8 / 128
        int j = (tid * 8) & 127;
        f32x4 c0 = *(const f32x4*)(x0 + flat);
        f32x4 c1 = *(const f32x4*)(x0 + flat + 4);
        float* od = out + (long long)(nodeblk + nn) * 384 + j;
        if (NT) {
            __builtin_nontemporal_store(c0, (f32x4*)od);
            __builtin_nontemporal_store(c1, (f32x4*)(od + 4));
        } else {
            *(f32x4*)od = c0;
            *(f32x4*)(od + 4) = c1;
        }
    }
    const int4* ip = (const int4*)(pne + node * K_);
    int4 i0 = ip[0], i1 = ip[1], i2 = ip[2], i3 = ip[3];
    float cnt = (float)((i0.x >= 0) + (i0.y >= 0) + (i0.z >= 0) + (i0.w >= 0) +
                        (i1.x >= 0) + (i1.y >= 0) + (i1.z >= 0) + (i1.w >= 0) +
                        (i2.x >= 0) + (i2.y >= 0) + (i2.z >= 0) + (i2.w >= 0) +
                        (i3.x >= 0) + (i3.y >= 0) + (i3.z >= 0) + (i3.w >= 0));
    const unsigned char* ebase = ee + (long long)b * (E_ * F_) + s16 * 8;
    float a0 = 0.f, a1 = 0.f, a2 = 0.f, a3 = 0.f;
    float a4 = 0.f, a5 = 0.f, a6 = 0.f, a7 = 0.f;
#ifdef HW_FP8
    #define PROC(pk) { \
        float m = ((pk) >= 0) ? 1.0f : 0.0f; \
        int eid = (pk) < 0 ? 0 : (pk); \
        uint2 v = *(const uint2*)(ebase + (long long)eid * F_); \
        f32x2 c0 = __builtin_amdgcn_cvt_pk_f32_fp8(v.x, false); \
        f32x2 c1 = __builtin_amdgcn_cvt_pk_f32_fp8(v.x, true); \
        f32x2 c2 = __builtin_amdgcn_cvt_pk_f32_fp8(v.y, false); \
        f32x2 c3 = __builtin_amdgcn_cvt_pk_f32_fp8(v.y, true); \
        a0 += m * c0.x; a1 += m * c0.y; a2 += m * c1.x; a3 += m * c1.y; \
        a4 += m * c2.x; a5 += m * c2.y; a6 += m * c3.x; a7 += m * c3.y; }
#else
    #define PROC(pk) { \
        float ms = ((pk) >= 0) ? 0x1p120f : 0.0f; \
        int eid = (pk) < 0 ? 0 : (pk); \
        uint2 v = *(const uint2*)(ebase + (long long)eid * F_); \
        a0 += ms * DECM(v.x); a1 += ms * DECM(v.x >> 8); \
        a2 += ms * DECM(v.x >> 16); a3 += ms * DECM(v.x >> 24); \
        a4 += ms * DECM(v.y); a5 += ms * DECM(v.y >> 8); \
        a6 += ms * DECM(v.y >> 16); a7 += ms * DECM(v.y >> 24); }
#endif
    PROC(i0.x) PROC(i0.y) PROC(i0.z) PROC(i0.w)
    PROC(i1.x) PROC(i1.y) PROC(i1.z) PROC(i1.w)
    PROC(i2.x) PROC(i2.y) PROC(i2.z) PROC(i2.w)
    PROC(i3.x) PROC(i3.y) PROC(i3.z) PROC(i3.w)
    #undef PROC
    float inv = 1.0f / (cnt + 1e-8f);
    a0 *= inv; a1 *= inv; a2 *= inv; a3 *= inv;
    a4 *= inv; a5 *= inv; a6 *= inv; a7 *= inv;
    float* po = out + (long long)node * 384 + col_off + s16 * 8;
    f32x4 o0 = (f32x4){a0, a1, a2, a3};
    f32x4 o1 = (f32x4){a4, a5, a6, a7};
    if (NT) {
        __builtin_nontemporal_store(o0, (f32x4*)po);
        __builtin_nontemporal_store(o1, (f32x4*)(po + 4));
    } else {
        *(f32x4*)po = o0;
        *(f32x4*)(po + 4) = o1;
    }
    if (xf8) {                          // x1 in fp8 (|x1| <= 1)
        uint2 p;
        p.x = pack_fp8x4(a0, a1, a2, a3);
        p.y = pack_fp8x4(a4, a5, a6, a7);
        *(uint2*)(xf8 + (long long)node * F_ + s16 * 8) = p;
    }
}

// ---------------- fallback kernels (separate-launch path) -------------------

template <int SRC, int DO_PNE>
__global__ void __launch_bounds__(256) edge_kernel(
    const void* xsrc, const int* edges_raw, const int* ne_raw, const int* mask,
    const int* flags, const unsigned short* wf, const float* bias,
    unsigned char* eout, int* pne) {
    __shared__ short xt[64 * F_];
    __shared__ int sids[64];
    edge_body<SRC, DO_PNE>(xt, sids, xsrc, edges_raw, ne_raw, mask, flags,
                           wf, bias, eout, pne);
}

__global__ void __launch_bounds__(256) agg_kernel(
    const unsigned char* ee, const int* pne, const float* x0, float* out,
    unsigned char* xf8, int col_off) {
    agg_body<0>(ee, pne, x0, out, xf8, col_off);
}

// ---------------- mega kernel: 4 phases, per-XCD barriers -------------------
// All inter-phase buffers (ebuf, pne, x1f8) are XCD-local by the batch-per-XCD
// swizzle; each XCD syncs only its own 256 blocks and flows independently.

__device__ __forceinline__ void xcd_bar(int* cnt, int xcd) {
    __syncthreads();
    if (threadIdx.x == 0) {
        int* c = cnt + xcd;
        __hip_atomic_fetch_add(c, 1, __ATOMIC_RELAXED, __HIP_MEMORY_SCOPE_AGENT);
        while (__hip_atomic_load(c, __ATOMIC_RELAXED, __HIP_MEMORY_SCOPE_AGENT) < 256) {
            __builtin_amdgcn_s_sleep(2);
        }
    }
    __syncthreads();
}

__global__ void __launch_bounds__(256, 8) mega_kernel(
    const float* __restrict__ x0, const int* __restrict__ edges_raw,
    const int* __restrict__ ne_raw, const int* __restrict__ mask,
    int* __restrict__ flags, const unsigned short* __restrict__ wf,
    const float* __restrict__ b1, const float* __restrict__ b2,
    unsigned char* __restrict__ ebuf, unsigned char* __restrict__ x1f8,
    int* __restrict__ pne, float* __restrict__ out) {
    __shared__ short xt[64 * F_];
    __shared__ int sids[64];
    int xcd = blockIdx.x & 7;
    int* cnt = flags + 4;
    // phase 1: edge round 1 (fp32 x0 source) + pne packing
    edge_body<1, 1>(xt, sids, x0, edges_raw, ne_raw, mask, flags, wf, b1, ebuf, pne);
    xcd_bar(cnt + 0, xcd);
    // phase 2: agg round 1 (+ x0 copy), writes x1 in fp8
    agg_body<1>(ebuf, pne, x0, out, x1f8, 128);
    xcd_bar(cnt + 8, xcd);
    // phase 3: edge round 2 (fp8 x1 source)
    edge_body<2, 0>(xt, sids, x1f8, edges_raw, ne_raw, mask, flags, wf + 16384, b2, ebuf, pne);
    xcd_bar(cnt + 16, xcd);
    // phase 4: agg round 2
    agg_body<1>(ebuf, pne, nullptr, out, nullptr, 256);
}

extern "C" void kernel_launch(void* const* d_in, const int* in_sizes, int n_in,
                              void* d_out, int out_size, void* d_ws, size_t ws_size,
                              hipStream_t stream) {
    const float* x0        = (const float*)d_in[0];
    const int*   edges_raw = (const int*)d_in[1];
    const int*   ne_raw    = (const int*)d_in[2];
    const int*   mask      = (const int*)d_in[3];
    const float* W1        = (const float*)d_in[4];
    const float* b1        = (const float*)d_in[5];
    const float* W2        = (const float*)d_in[6];
    const float* b2        = (const float*)d_in[7];
    float* out = (float*)d_out;
    char* ws = (char*)d_ws;

    unsigned char*  ebuf = (unsigned char*)ws;                    // B*E*F fp8 = 16 MB
    unsigned char*  x1f8 = (unsigned char*)(ws + 16777216);       // B*N*F fp8 = 4 MB
    unsigned short* wf   = (unsigned short*)(ws + 20971520);      // 2*128*128 = 64 KB
    int* flags           = (int*)(ws + 21037056);                 // flags + 24 counters
    int* pne             = (int*)(ws + 21102592);                 // B*N*K     = 2 MB

    wprep<<<17, 256, 0, stream>>>(W1, W2, edges_raw, ne_raw, wf, flags);

    // co-residency check for the spin-barrier mega kernel (deterministic)
    int nb = 0;
    (void)hipOccupancyMaxActiveBlocksPerMultiprocessor(&nb, (const void*)mega_kernel, 256, 0);
    if (nb >= 8) {
        mega_kernel<<<NBLK, 256, 0, stream>>>(x0, edges_raw, ne_raw, mask, flags,
                                              wf, b1, b2, ebuf, x1f8, pne, out);
    } else {
        edge_kernel<1, 1><<<2048, 256, 0, stream>>>(x0, edges_raw, ne_raw, mask,
                                                    flags, wf, b1, ebuf, pne);
        agg_kernel<<<2048, 256, 0, stream>>>(ebuf, pne, x0, out, x1f8, 128);
        edge_kernel<2, 0><<<2048, 256, 0, stream>>>(x1f8, edges_raw, ne_raw, mask,
                                                    flags, wf + 16384, b2, ebuf, pne);
        agg_kernel<<<2048, 256, 0, stream>>>(ebuf, pne, nullptr, out, nullptr, 256);
    }
}

// Round 17
// 48.591 us; speedup vs baseline: 1.6642x; 1.5333x over previous
//
#include <hip/hip_runtime.h>
#include <hip/hip_bf16.h>

typedef __attribute__((ext_vector_type(8))) short short8;
typedef __attribute__((ext_vector_type(4))) float f32x4;
typedef __attribute__((ext_vector_type(2))) float f32x2;

#define B_ 8
#define N_ 4096
#define E_ 16384
#define K_ 16
#define F_ 128

#if defined(__has_builtin)
#  if __has_builtin(__builtin_amdgcn_cvt_pk_f32_fp8) && __has_builtin(__builtin_amdgcn_cvt_pk_fp8_f32)
#    define HW_FP8 1
#  endif
#endif

__device__ __forceinline__ unsigned short f2bf(float f) {
    union { float f; unsigned int u; } c; c.f = f;
    unsigned int u = c.u;
    unsigned int r = (u + 0x7fffu + ((u >> 16) & 1u)) >> 16;
    return (unsigned short)r;
}
__device__ __forceinline__ float fast_tanh(float x) {
    float e = __expf(2.0f * x);
    return 1.0f - 2.0f / (e + 1.0f);
}

// ---- fp8 e4m3 codec (HW when available; matched manual encode/decode pair) ----
__device__ __forceinline__ unsigned int f2fp8_manual(float v) {
    unsigned int u = __float_as_uint(v * 0x1p-120f);
    unsigned int r = (u & 0x7fffffffu) + 0x7ffffu + ((u >> 20) & 1u);
    return ((r >> 20) & 0x7fu) | ((u >> 24) & 0x80u);
}
__device__ __forceinline__ unsigned int pack_fp8x4(float t0, float t1, float t2, float t3) {
#ifdef HW_FP8
    int wd = 0;
    wd = __builtin_amdgcn_cvt_pk_fp8_f32(t0, t1, wd, false);
    wd = __builtin_amdgcn_cvt_pk_fp8_f32(t2, t3, wd, true);
    return (unsigned int)wd;
#else
    return f2fp8_manual(t0) | (f2fp8_manual(t1) << 8) |
           (f2fp8_manual(t2) << 16) | (f2fp8_manual(t3) << 24);
#endif
}
#ifndef HW_FP8
#define DECM(bb) __int_as_float((int)((((bb) & 0x80u) << 24) | (((bb) & 0x7fu) << 20)))
#endif

// ---- detect whether an "integer" input buffer is int64 (high words all 0) ----
__device__ __forceinline__ int detect64(const int* raw) {
    int o = 0;
    #pragma unroll
    for (int i = 1; i < 128; i += 2) o |= raw[i];
    return (o == 0) ? 1 : 0;
}

// 17 blocks: [0,16) build wf (W1,W2 in MFMA fragment order, bf16);
// block 16: i64/i32 flags.
//   wf[((nt*4+g)*64+l)*8+t] = W[nt*16+(l&15)][g*32+8*(l>>4)+t]
__global__ void wprep(const float* __restrict__ W1, const float* __restrict__ W2,
                      const int* __restrict__ edges_raw, const int* __restrict__ ne_raw,
                      unsigned short* __restrict__ wf, int* __restrict__ flags) {
    int blk = blockIdx.x, tid = threadIdx.x;
    if (blk == 16) {
        if (tid == 0) {
            flags[0] = detect64(edges_raw);
            flags[1] = detect64(ne_raw);
        }
        return;
    }
    int gtid = blk * 256 + tid;    // 0..4095
    int wsel = gtid >> 11;
    int q = gtid & 2047;
    int lane = q & 63;
    int gq = q >> 6;
    int nt = gq >> 2, g = gq & 3;
    const float* W = wsel ? W2 : W1;
    int j = nt * 16 + (lane & 15);
    int kbase = g * 32 + 8 * (lane >> 4);
    unsigned short* d = wf + wsel * 16384 + q * 8;
    #pragma unroll
    for (int t = 0; t < 8; ++t) d[t] = f2bf(W[j * 128 + kbase + t]);
}

// Node transform: y[b,n,:] = fp8( tanh( x[b,n,:] @ W^T + bias ) )  -- DENSE.
// (Key identity: edge_emb[b,e] depends only on sender(e), so per-NODE
// transforms suffice; aggregation indexes y via sid2[n,k]=sender[ne[n,k]].)
// 64 consecutive rows/block, 4 waves, A=W (from wf), B=x^T. No gather.
// SRC: 1 = fp32 rows (x0), 2 = fp8 rows (x1).
// DO_AUX (round 1): also copy x0 rows -> out[:,0:128] (chunks already in
// registers) and pack sid2 (4 coalesced entries/thread, written XCD-local).
template <int SRC, int DO_AUX>
__global__ void __launch_bounds__(256) node_kernel(
    const void* __restrict__ xsrc, const int* __restrict__ edges_raw,
    const int* __restrict__ ne_raw, const int* __restrict__ mask,
    const int* __restrict__ flags, const unsigned short* __restrict__ wf,
    const float* __restrict__ bias, unsigned char* __restrict__ y,
    float* __restrict__ out, int* __restrict__ sid2) {
    __shared__ short xt[64 * F_];   // 16 KB, chunk-swizzled
    int tid = threadIdx.x;
    int swz = (blockIdx.x & 7) * 64 + (blockIdx.x >> 3);   // batch-per-XCD (512 blocks)
    int b = swz >> 6;
    int r0 = (swz & 63) * 64;          // first node row of this block
    if (DO_AUX) {                      // sid2[i] = mask[i] ? sender[ne[i]] : -1
        int s64e = flags[0], s64n = flags[1];
        int base = swz * 1024;         // 512 blocks x 1024 = B*N*K entries
        #pragma unroll
        for (int t = 0; t < 4; ++t) {
            int i = base + t * 256 + tid;
            int bb = i >> 16;          // batch of entry (N*K = 65536)
            int eid = s64n ? ne_raw[2 * (long long)i] : ne_raw[i];
            long long ei = (long long)(bb * E_ + eid);
            int s = s64e ? edges_raw[6 * ei] : edges_raw[3 * ei];
            sid2[i] = mask[i] ? s : -1;
        }
    }
    // stage 64 consecutive rows into LDS as bf16; 16B chunks, pch = ch^(row&15)
    #pragma unroll
    for (int c = 0; c < 4; ++c) {
        int ci = tid + 256 * c;         // 0..1023
        int row = ci >> 4, ch = ci & 15;
        int pch = ch ^ (row & 15);
        long long gnode = (long long)(b * N_ + r0 + row);
        if (SRC == 1) {
            const float* src = (const float*)xsrc + gnode * F_ + ch * 8;
            float4 v0 = *(const float4*)src;
            float4 v1 = *(const float4*)(src + 4);
            ushort4 h0, h1;
            h0.x = f2bf(v0.x); h0.y = f2bf(v0.y); h0.z = f2bf(v0.z); h0.w = f2bf(v0.w);
            h1.x = f2bf(v1.x); h1.y = f2bf(v1.y); h1.z = f2bf(v1.z); h1.w = f2bf(v1.w);
            *(ushort4*)&xt[row * F_ + pch * 8] = h0;
            *(ushort4*)&xt[row * F_ + pch * 8 + 4] = h1;
            if (DO_AUX) {               // x0 -> out[:, 0:128] (coalesced)
                float* od = out + gnode * 384 + ch * 8;
                *(float4*)od = v0;
                *(float4*)(od + 4) = v1;
            }
        } else {
            const unsigned char* src = (const unsigned char*)xsrc + gnode * F_ + ch * 8;
            uint2 v = *(const uint2*)src;
            short8 h;
#ifdef HW_FP8
            f32x2 c0 = __builtin_amdgcn_cvt_pk_f32_fp8(v.x, false);
            f32x2 c1 = __builtin_amdgcn_cvt_pk_f32_fp8(v.x, true);
            f32x2 c2 = __builtin_amdgcn_cvt_pk_f32_fp8(v.y, false);
            f32x2 c3 = __builtin_amdgcn_cvt_pk_f32_fp8(v.y, true);
            h[0] = (short)f2bf(c0.x); h[1] = (short)f2bf(c0.y);
            h[2] = (short)f2bf(c1.x); h[3] = (short)f2bf(c1.y);
            h[4] = (short)f2bf(c2.x); h[5] = (short)f2bf(c2.y);
            h[6] = (short)f2bf(c3.x); h[7] = (short)f2bf(c3.y);
#else
            h[0] = (short)f2bf(0x1p120f * DECM(v.x));
            h[1] = (short)f2bf(0x1p120f * DECM(v.x >> 8));
            h[2] = (short)f2bf(0x1p120f * DECM(v.x >> 16));
            h[3] = (short)f2bf(0x1p120f * DECM(v.x >> 24));
            h[4] = (short)f2bf(0x1p120f * DECM(v.y));
            h[5] = (short)f2bf(0x1p120f * DECM(v.y >> 8));
            h[6] = (short)f2bf(0x1p120f * DECM(v.y >> 16));
            h[7] = (short)f2bf(0x1p120f * DECM(v.y >> 24));
#endif
            *(short8*)&xt[row * F_ + pch * 8] = h;
        }
    }
    __syncthreads();
    int w = tid >> 6, lane = tid & 63;
    int rr = w * 16 + (lane & 15);        // this wave's 16 node rows
    short8 bfr[4];
    #pragma unroll
    for (int g = 0; g < 4; ++g) {
        int pch = (g * 4 + (lane >> 4)) ^ (rr & 15);
        bfr[g] = *(const short8*)&xt[rr * F_ + pch * 8];
    }
    int jq = (lane >> 4) * 4;             // j sub-offset of this lane's 4 regs
    long long ybyte = ((long long)(b * N_ + r0 + w * 16 + (lane & 15))) * F_;  // fp8 row = 128B
    #pragma unroll
    for (int nt = 0; nt < 8; ++nt) {
        f32x4 acc = (f32x4){0.f, 0.f, 0.f, 0.f};
        #pragma unroll
        for (int g = 0; g < 4; ++g) {
            short8 afr = *(const short8*)(wf + ((nt * 4 + g) * 64 + lane) * 8);
            acc = __builtin_amdgcn_mfma_f32_16x16x32_bf16(afr, bfr[g], acc, 0, 0, 0);
        }
        float4 bv = *(const float4*)(bias + nt * 16 + jq);
        float t0 = fast_tanh(acc[0] + bv.x);
        float t1 = fast_tanh(acc[1] + bv.y);
        float t2 = fast_tanh(acc[2] + bv.z);
        float t3 = fast_tanh(acc[3] + bv.w);
        *(unsigned int*)(y + ybyte + nt * 16 + jq) = pack_fp8x4(t0, t1, t2, t3);
    }
}

// x_next[b,n,:] = ( sum_k y[b, sid2[n,k], :] ) / (cnt + eps)
// ONE node per 16-lane quarter: lane owns 8 cols (8B fp8), loops all 16 ks
// -> 16 independent 8B gathers in flight, no cross-lane reduce. y slice =
// 512 KB/batch -> L2-resident per XCD (batch-per-XCD swizzle).
__global__ void __launch_bounds__(256) agg_kernel(
    const unsigned char* __restrict__ y, const int* __restrict__ sid2,
    float* __restrict__ out, unsigned char* __restrict__ xf8, int col_off) {
    int tid = threadIdx.x;
    int swz = (blockIdx.x & 7) * 256 + (blockIdx.x >> 3);   // batch-per-XCD
    int nodeblk = swz * 16;            // 16 nodes per block
    int wid = tid >> 6, lane = tid & 63;
    int qt = lane >> 4, s16 = lane & 15;
    int node = nodeblk + wid * 4 + qt;
    int b = node >> 12;                // N=4096
    const int4* ip = (const int4*)(sid2 + node * K_);
    int4 i0 = ip[0], i1 = ip[1], i2 = ip[2], i3 = ip[3];
    float cnt = (float)((i0.x >= 0) + (i0.y >= 0) + (i0.z >= 0) + (i0.w >= 0) +
                        (i1.x >= 0) + (i1.y >= 0) + (i1.z >= 0) + (i1.w >= 0) +
                        (i2.x >= 0) + (i2.y >= 0) + (i2.z >= 0) + (i2.w >= 0) +
                        (i3.x >= 0) + (i3.y >= 0) + (i3.z >= 0) + (i3.w >= 0));
    const unsigned char* ybase = y + (long long)b * (N_ * F_) + s16 * 8;
    float a0 = 0.f, a1 = 0.f, a2 = 0.f, a3 = 0.f;
    float a4 = 0.f, a5 = 0.f, a6 = 0.f, a7 = 0.f;
#ifdef HW_FP8
    #define PROC(pk) { \
        float m = ((pk) >= 0) ? 1.0f : 0.0f; \
        int nid = (pk) < 0 ? 0 : (pk); \
        uint2 v = *(const uint2*)(ybase + (long long)nid * F_); \
        f32x2 c0 = __builtin_amdgcn_cvt_pk_f32_fp8(v.x, false); \
        f32x2 c1 = __builtin_amdgcn_cvt_pk_f32_fp8(v.x, true); \
        f32x2 c2 = __builtin_amdgcn_cvt_pk_f32_fp8(v.y, false); \
        f32x2 c3 = __builtin_amdgcn_cvt_pk_f32_fp8(v.y, true); \
        a0 += m * c0.x; a1 += m * c0.y; a2 += m * c1.x; a3 += m * c1.y; \
        a4 += m * c2.x; a5 += m * c2.y; a6 += m * c3.x; a7 += m * c3.y; }
#else
    #define PROC(pk) { \
        float ms = ((pk) >= 0) ? 0x1p120f : 0.0f; \
        int nid = (pk) < 0 ? 0 : (pk); \
        uint2 v = *(const uint2*)(ybase + (long long)nid * F_); \
        a0 += ms * DECM(v.x); a1 += ms * DECM(v.x >> 8); \
        a2 += ms * DECM(v.x >> 16); a3 += ms * DECM(v.x >> 24); \
        a4 += ms * DECM(v.y); a5 += ms * DECM(v.y >> 8); \
        a6 += ms * DECM(v.y >> 16); a7 += ms * DECM(v.y >> 24); }
#endif
    PROC(i0.x) PROC(i0.y) PROC(i0.z) PROC(i0.w)
    PROC(i1.x) PROC(i1.y) PROC(i1.z) PROC(i1.w)
    PROC(i2.x) PROC(i2.y) PROC(i2.z) PROC(i2.w)
    PROC(i3.x) PROC(i3.y) PROC(i3.z) PROC(i3.w)
    #undef PROC
    float inv = 1.0f / (cnt + 1e-8f);
    a0 *= inv; a1 *= inv; a2 *= inv; a3 *= inv;
    a4 *= inv; a5 *= inv; a6 *= inv; a7 *= inv;
    float* po = out + (long long)node * 384 + col_off + s16 * 8;
    *(f32x4*)po = (f32x4){a0, a1, a2, a3};
    *(f32x4*)(po + 4) = (f32x4){a4, a5, a6, a7};
    if (xf8) {                          // x1 in fp8 (|x1| <= 1)
        uint2 p;
        p.x = pack_fp8x4(a0, a1, a2, a3);
        p.y = pack_fp8x4(a4, a5, a6, a7);
        *(uint2*)(xf8 + (long long)node * F_ + s16 * 8) = p;
    }
}

extern "C" void kernel_launch(void* const* d_in, const int* in_sizes, int n_in,
                              void* d_out, int out_size, void* d_ws, size_t ws_size,
                              hipStream_t stream) {
    const float* x0        = (const float*)d_in[0];
    const int*   edges_raw = (const int*)d_in[1];
    const int*   ne_raw    = (const int*)d_in[2];
    const int*   mask      = (const int*)d_in[3];
    const float* W1        = (const float*)d_in[4];
    const float* b1        = (const float*)d_in[5];
    const float* W2        = (const float*)d_in[6];
    const float* b2        = (const float*)d_in[7];
    float* out = (float*)d_out;
    char* ws = (char*)d_ws;

    unsigned char*  ybuf = (unsigned char*)ws;                    // B*N*F fp8 = 4 MB
    unsigned char*  x1f8 = (unsigned char*)(ws + 4194304);        // B*N*F fp8 = 4 MB
    unsigned short* wf   = (unsigned short*)(ws + 8388608);       // 2*128*128 = 64 KB
    int* flags           = (int*)(ws + 8454144);                  // 2 x int32
    int* sid2            = (int*)(ws + 8519680);                  // B*N*K     = 2 MB

    wprep<<<17, 256, 0, stream>>>(W1, W2, edges_raw, ne_raw, wf, flags);
    // round 1: dense node transform (+ x0 copy + sid2 pack), then aggregate
    node_kernel<1, 1><<<512, 256, 0, stream>>>(x0, edges_raw, ne_raw, mask,
                                               flags, wf, b1, ybuf, out, sid2);
    agg_kernel<<<2048, 256, 0, stream>>>(ybuf, sid2, out, x1f8, 128);
    // round 2: dense node transform of fp8 x1, then aggregate
    node_kernel<2, 0><<<512, 256, 0, stream>>>(x1f8, edges_raw, ne_raw, mask,
                                               flags, wf + 16384, b2, ybuf, nullptr, nullptr);
    agg_kernel<<<2048, 256, 0, stream>>>(ybuf, sid2, out, nullptr, 256);
}

// Round 18
// 47.131 us; speedup vs baseline: 1.7157x; 1.0310x over previous
//
#include <hip/hip_runtime.h>
#include <hip/hip_bf16.h>

typedef __attribute__((ext_vector_type(8))) short short8;
typedef __attribute__((ext_vector_type(4))) float f32x4;
typedef __attribute__((ext_vector_type(2))) float f32x2;

#define B_ 8
#define N_ 4096
#define E_ 16384
#define K_ 16
#define F_ 128

#if defined(__has_builtin)
#  if __has_builtin(__builtin_amdgcn_cvt_pk_f32_fp8) && __has_builtin(__builtin_amdgcn_cvt_pk_fp8_f32)
#    define HW_FP8 1
#  endif
#endif

__device__ __forceinline__ unsigned short f2bf(float f) {
    union { float f; unsigned int u; } c; c.f = f;
    unsigned int u = c.u;
    unsigned int r = (u + 0x7fffu + ((u >> 16) & 1u)) >> 16;
    return (unsigned short)r;
}
__device__ __forceinline__ float fast_tanh(float x) {
    float e = __expf(2.0f * x);
    return 1.0f - 2.0f / (e + 1.0f);
}

// ---- fp8 e4m3 codec (HW when available; matched manual encode/decode pair) ----
__device__ __forceinline__ unsigned int f2fp8_manual(float v) {
    unsigned int u = __float_as_uint(v * 0x1p-120f);
    unsigned int r = (u & 0x7fffffffu) + 0x7ffffu + ((u >> 20) & 1u);
    return ((r >> 20) & 0x7fu) | ((u >> 24) & 0x80u);
}
__device__ __forceinline__ unsigned int pack_fp8x4(float t0, float t1, float t2, float t3) {
#ifdef HW_FP8
    int wd = 0;
    wd = __builtin_amdgcn_cvt_pk_fp8_f32(t0, t1, wd, false);
    wd = __builtin_amdgcn_cvt_pk_fp8_f32(t2, t3, wd, true);
    return (unsigned int)wd;
#else
    return f2fp8_manual(t0) | (f2fp8_manual(t1) << 8) |
           (f2fp8_manual(t2) << 16) | (f2fp8_manual(t3) << 24);
#endif
}
#ifndef HW_FP8
#define DECM(bb) __int_as_float((int)((((bb) & 0x80u) << 24) | (((bb) & 0x7fu) << 20)))
#endif

// ---- detect whether an "integer" input buffer is int64 (high words all 0) ----
__device__ __forceinline__ int detect64(const int* raw) {
    int o = 0;
    #pragma unroll
    for (int i = 1; i < 128; i += 2) o |= raw[i];
    return (o == 0) ? 1 : 0;
}

// 17 blocks: [0,16) build wf (W1,W2 in MFMA fragment order, bf16);
// block 16: i64/i32 flags.
//   wf[((nt*4+g)*64+l)*8+t] = W[nt*16+(l&15)][g*32+8*(l>>4)+t]
__global__ void wprep(const float* __restrict__ W1, const float* __restrict__ W2,
                      const int* __restrict__ edges_raw, const int* __restrict__ ne_raw,
                      unsigned short* __restrict__ wf, int* __restrict__ flags) {
    int blk = blockIdx.x, tid = threadIdx.x;
    if (blk == 16) {
        if (tid == 0) {
            flags[0] = detect64(edges_raw);
            flags[1] = detect64(ne_raw);
        }
        return;
    }
    int gtid = blk * 256 + tid;    // 0..4095
    int wsel = gtid >> 11;
    int q = gtid & 2047;
    int lane = q & 63;
    int gq = q >> 6;
    int nt = gq >> 2, g = gq & 3;
    const float* W = wsel ? W2 : W1;
    int j = nt * 16 + (lane & 15);
    int kbase = g * 32 + 8 * (lane >> 4);
    unsigned short* d = wf + wsel * 16384 + q * 8;
    #pragma unroll
    for (int t = 0; t < 8; ++t) d[t] = f2bf(W[j * 128 + kbase + t]);
}

// Node transform round 1: y[b,n,:] = fp8( tanh( x0[b,n,:] @ W1^T + b1 ) ), DENSE.
// Also: copy x0 -> out[:,0:128] and pack sid2[i] = mask[i] ? sender[ne[i]] : -1.
// 64 consecutive rows/block, 4 waves, A=W (from wf), B=x^T.
__global__ void __launch_bounds__(256) node_kernel(
    const float* __restrict__ xsrc, const int* __restrict__ edges_raw,
    const int* __restrict__ ne_raw, const int* __restrict__ mask,
    const int* __restrict__ flags, const unsigned short* __restrict__ wf,
    const float* __restrict__ bias, unsigned char* __restrict__ y,
    float* __restrict__ out, int* __restrict__ sid2) {
    __shared__ short xt[64 * F_];   // 16 KB, chunk-swizzled
    int tid = threadIdx.x;
    int swz = (blockIdx.x & 7) * 64 + (blockIdx.x >> 3);   // batch-per-XCD (512 blocks)
    int b = swz >> 6;
    int r0 = (swz & 63) * 64;          // first node row of this block
    {                                  // sid2 pack: 4 coalesced entries/thread
        int s64e = flags[0], s64n = flags[1];
        int base = swz * 1024;         // 512 blocks x 1024 = B*N*K entries
        #pragma unroll
        for (int t = 0; t < 4; ++t) {
            int i = base + t * 256 + tid;
            int bb = i >> 16;          // batch of entry (N*K = 65536)
            int eid = s64n ? ne_raw[2 * (long long)i] : ne_raw[i];
            long long ei = (long long)(bb * E_ + eid);
            int s = s64e ? edges_raw[6 * ei] : edges_raw[3 * ei];
            sid2[i] = mask[i] ? s : -1;
        }
    }
    // stage 64 consecutive fp32 rows into LDS as bf16; pch = ch^(row&15)
    #pragma unroll
    for (int c = 0; c < 4; ++c) {
        int ci = tid + 256 * c;         // 0..1023
        int row = ci >> 4, ch = ci & 15;
        int pch = ch ^ (row & 15);
        long long gnode = (long long)(b * N_ + r0 + row);
        const float* src = xsrc + gnode * F_ + ch * 8;
        float4 v0 = *(const float4*)src;
        float4 v1 = *(const float4*)(src + 4);
        ushort4 h0, h1;
        h0.x = f2bf(v0.x); h0.y = f2bf(v0.y); h0.z = f2bf(v0.z); h0.w = f2bf(v0.w);
        h1.x = f2bf(v1.x); h1.y = f2bf(v1.y); h1.z = f2bf(v1.z); h1.w = f2bf(v1.w);
        *(ushort4*)&xt[row * F_ + pch * 8] = h0;
        *(ushort4*)&xt[row * F_ + pch * 8 + 4] = h1;
        float* od = out + gnode * 384 + ch * 8;   // x0 -> out[:,0:128]
        *(float4*)od = v0;
        *(float4*)(od + 4) = v1;
    }
    __syncthreads();
    int w = tid >> 6, lane = tid & 63;
    int rr = w * 16 + (lane & 15);        // this wave's 16 node rows
    short8 bfr[4];
    #pragma unroll
    for (int g = 0; g < 4; ++g) {
        int pch = (g * 4 + (lane >> 4)) ^ (rr & 15);
        bfr[g] = *(const short8*)&xt[rr * F_ + pch * 8];
    }
    int jq = (lane >> 4) * 4;
    long long ybyte = ((long long)(b * N_ + r0 + w * 16 + (lane & 15))) * F_;
    #pragma unroll
    for (int nt = 0; nt < 8; ++nt) {
        f32x4 acc = (f32x4){0.f, 0.f, 0.f, 0.f};
        #pragma unroll
        for (int g = 0; g < 4; ++g) {
            short8 afr = *(const short8*)(wf + ((nt * 4 + g) * 64 + lane) * 8);
            acc = __builtin_amdgcn_mfma_f32_16x16x32_bf16(afr, bfr[g], acc, 0, 0, 0);
        }
        float4 bv = *(const float4*)(bias + nt * 16 + jq);
        float t0 = fast_tanh(acc[0] + bv.x);
        float t1 = fast_tanh(acc[1] + bv.y);
        float t2 = fast_tanh(acc[2] + bv.z);
        float t3 = fast_tanh(acc[3] + bv.w);
        *(unsigned int*)(y + ybyte + nt * 16 + jq) = pack_fp8x4(t0, t1, t2, t3);
    }
}

// FUSED agg1 + node2: block owns 64 consecutive nodes.
// Phase A (agg): quarter (wid,qt) aggregates 4 nodes (rows wid*16+qt*4+t);
//   lane owns 8 cols -> 64 independent 8B gathers in flight per lane.
//   x1 row -> out[:,128:256] (fp32) AND directly into the LDS MFMA tile (bf16).
// Phase B (node2): dense MFMA transform of the 64 x1 rows -> y2 (fp8).
__global__ void __launch_bounds__(256) aggnode_kernel(
    const unsigned char* __restrict__ y1, const int* __restrict__ sid2,
    const unsigned short* __restrict__ wf2, const float* __restrict__ bias,
    float* __restrict__ out, unsigned char* __restrict__ y2) {
    __shared__ short xt[64 * F_];   // 16 KB
    int tid = threadIdx.x;
    int swz = (blockIdx.x & 7) * 64 + (blockIdx.x >> 3);   // batch-per-XCD (512 blocks)
    int b = swz >> 6;
    int r0 = (swz & 63) * 64;          // first node row of this block
    int wid = tid >> 6, lane = tid & 63;
    int qt = lane >> 4, s16 = lane & 15;
    const unsigned char* ybase = y1 + (long long)b * (N_ * F_) + s16 * 8;
    #pragma unroll
    for (int t = 0; t < 4; ++t) {
        int row = wid * 16 + qt * 4 + t;
        long long gnode = (long long)(b * N_ + r0 + row);
        const int4* ip = (const int4*)(sid2 + gnode * K_);
        int4 i0 = ip[0], i1 = ip[1], i2 = ip[2], i3 = ip[3];
        float cnt = (float)((i0.x >= 0) + (i0.y >= 0) + (i0.z >= 0) + (i0.w >= 0) +
                            (i1.x >= 0) + (i1.y >= 0) + (i1.z >= 0) + (i1.w >= 0) +
                            (i2.x >= 0) + (i2.y >= 0) + (i2.z >= 0) + (i2.w >= 0) +
                            (i3.x >= 0) + (i3.y >= 0) + (i3.z >= 0) + (i3.w >= 0));
        float a0 = 0.f, a1 = 0.f, a2 = 0.f, a3 = 0.f;
        float a4 = 0.f, a5 = 0.f, a6 = 0.f, a7 = 0.f;
#ifdef HW_FP8
        #define PROC(pk) { \
            float m = ((pk) >= 0) ? 1.0f : 0.0f; \
            int nid = (pk) < 0 ? 0 : (pk); \
            uint2 v = *(const uint2*)(ybase + (long long)nid * F_); \
            f32x2 c0 = __builtin_amdgcn_cvt_pk_f32_fp8(v.x, false); \
            f32x2 c1 = __builtin_amdgcn_cvt_pk_f32_fp8(v.x, true); \
            f32x2 c2 = __builtin_amdgcn_cvt_pk_f32_fp8(v.y, false); \
            f32x2 c3 = __builtin_amdgcn_cvt_pk_f32_fp8(v.y, true); \
            a0 += m * c0.x; a1 += m * c0.y; a2 += m * c1.x; a3 += m * c1.y; \
            a4 += m * c2.x; a5 += m * c2.y; a6 += m * c3.x; a7 += m * c3.y; }
#else
        #define PROC(pk) { \
            float ms = ((pk) >= 0) ? 0x1p120f : 0.0f; \
            int nid = (pk) < 0 ? 0 : (pk); \
            uint2 v = *(const uint2*)(ybase + (long long)nid * F_); \
            a0 += ms * DECM(v.x); a1 += ms * DECM(v.x >> 8); \
            a2 += ms * DECM(v.x >> 16); a3 += ms * DECM(v.x >> 24); \
            a4 += ms * DECM(v.y); a5 += ms * DECM(v.y >> 8); \
            a6 += ms * DECM(v.y >> 16); a7 += ms * DECM(v.y >> 24); }
#endif
        PROC(i0.x) PROC(i0.y) PROC(i0.z) PROC(i0.w)
        PROC(i1.x) PROC(i1.y) PROC(i1.z) PROC(i1.w)
        PROC(i2.x) PROC(i2.y) PROC(i2.z) PROC(i2.w)
        PROC(i3.x) PROC(i3.y) PROC(i3.z) PROC(i3.w)
        #undef PROC
        float inv = 1.0f / (cnt + 1e-8f);
        a0 *= inv; a1 *= inv; a2 *= inv; a3 *= inv;
        a4 *= inv; a5 *= inv; a6 *= inv; a7 *= inv;
        float* po = out + gnode * 384 + 128 + s16 * 8;
        *(f32x4*)po = (f32x4){a0, a1, a2, a3};
        *(f32x4*)(po + 4) = (f32x4){a4, a5, a6, a7};
        // x1 (bf16) straight into the MFMA staging tile; chunk = s16
        int pch = s16 ^ (row & 15);
        short8 h;
        h[0] = (short)f2bf(a0); h[1] = (short)f2bf(a1);
        h[2] = (short)f2bf(a2); h[3] = (short)f2bf(a3);
        h[4] = (short)f2bf(a4); h[5] = (short)f2bf(a5);
        h[6] = (short)f2bf(a6); h[7] = (short)f2bf(a7);
        *(short8*)&xt[row * F_ + pch * 8] = h;
    }
    __syncthreads();
    // phase B: dense transform of the 64 x1 rows -> y2
    int rr = wid * 16 + (lane & 15);
    short8 bfr[4];
    #pragma unroll
    for (int g = 0; g < 4; ++g) {
        int pch = (g * 4 + (lane >> 4)) ^ (rr & 15);
        bfr[g] = *(const short8*)&xt[rr * F_ + pch * 8];
    }
    int jq = (lane >> 4) * 4;
    long long ybyte = ((long long)(b * N_ + r0 + wid * 16 + (lane & 15))) * F_;
    #pragma unroll
    for (int nt = 0; nt < 8; ++nt) {
        f32x4 acc = (f32x4){0.f, 0.f, 0.f, 0.f};
        #pragma unroll
        for (int g = 0; g < 4; ++g) {
            short8 afr = *(const short8*)(wf2 + ((nt * 4 + g) * 64 + lane) * 8);
            acc = __builtin_amdgcn_mfma_f32_16x16x32_bf16(afr, bfr[g], acc, 0, 0, 0);
        }
        float4 bv = *(const float4*)(bias + nt * 16 + jq);
        float t0 = fast_tanh(acc[0] + bv.x);
        float t1 = fast_tanh(acc[1] + bv.y);
        float t2 = fast_tanh(acc[2] + bv.z);
        float t3 = fast_tanh(acc[3] + bv.w);
        *(unsigned int*)(y2 + ybyte + nt * 16 + jq) = pack_fp8x4(t0, t1, t2, t3);
    }
}

// final agg: x2[b,n,:] = ( sum_k y2[b, sid2[n,k], :] ) / (cnt + eps)
// ONE node per 16-lane quarter; 16 independent 8B gathers in flight.
__global__ void __launch_bounds__(256) agg_kernel(
    const unsigned char* __restrict__ y, const int* __restrict__ sid2,
    float* __restrict__ out, int col_off) {
    int tid = threadIdx.x;
    int swz = (blockIdx.x & 7) * 256 + (blockIdx.x >> 3);   // batch-per-XCD
    int nodeblk = swz * 16;            // 16 nodes per block
    int wid = tid >> 6, lane = tid & 63;
    int qt = lane >> 4, s16 = lane & 15;
    int node = nodeblk + wid * 4 + qt;
    int b = node >> 12;                // N=4096
    const int4* ip = (const int4*)(sid2 + node * K_);
    int4 i0 = ip[0], i1 = ip[1], i2 = ip[2], i3 = ip[3];
    float cnt = (float)((i0.x >= 0) + (i0.y >= 0) + (i0.z >= 0) + (i0.w >= 0) +
                        (i1.x >= 0) + (i1.y >= 0) + (i1.z >= 0) + (i1.w >= 0) +
                        (i2.x >= 0) + (i2.y >= 0) + (i2.z >= 0) + (i2.w >= 0) +
                        (i3.x >= 0) + (i3.y >= 0) + (i3.z >= 0) + (i3.w >= 0));
    const unsigned char* ybase = y + (long long)b * (N_ * F_) + s16 * 8;
    float a0 = 0.f, a1 = 0.f, a2 = 0.f, a3 = 0.f;
    float a4 = 0.f, a5 = 0.f, a6 = 0.f, a7 = 0.f;
#ifdef HW_FP8
    #define PROC(pk) { \
        float m = ((pk) >= 0) ? 1.0f : 0.0f; \
        int nid = (pk) < 0 ? 0 : (pk); \
        uint2 v = *(const uint2*)(ybase + (long long)nid * F_); \
        f32x2 c0 = __builtin_amdgcn_cvt_pk_f32_fp8(v.x, false); \
        f32x2 c1 = __builtin_amdgcn_cvt_pk_f32_fp8(v.x, true); \
        f32x2 c2 = __builtin_amdgcn_cvt_pk_f32_fp8(v.y, false); \
        f32x2 c3 = __builtin_amdgcn_cvt_pk_f32_fp8(v.y, true); \
        a0 += m * c0.x; a1 += m * c0.y; a2 += m * c1.x; a3 += m * c1.y; \
        a4 += m * c2.x; a5 += m * c2.y; a6 += m * c3.x; a7 += m * c3.y; }
#else
    #define PROC(pk) { \
        float ms = ((pk) >= 0) ? 0x1p120f : 0.0f; \
        int nid = (pk) < 0 ? 0 : (pk); \
        uint2 v = *(const uint2*)(ybase + (long long)nid * F_); \
        a0 += ms * DECM(v.x); a1 += ms * DECM(v.x >> 8); \
        a2 += ms * DECM(v.x >> 16); a3 += ms * DECM(v.x >> 24); \
        a4 += ms * DECM(v.y); a5 += ms * DECM(v.y >> 8); \
        a6 += ms * DECM(v.y >> 16); a7 += ms * DECM(v.y >> 24); }
#endif
    PROC(i0.x) PROC(i0.y) PROC(i0.z) PROC(i0.w)
    PROC(i1.x) PROC(i1.y) PROC(i1.z) PROC(i1.w)
    PROC(i2.x) PROC(i2.y) PROC(i2.z) PROC(i2.w)
    PROC(i3.x) PROC(i3.y) PROC(i3.z) PROC(i3.w)
    #undef PROC
    float inv = 1.0f / (cnt + 1e-8f);
    a0 *= inv; a1 *= inv; a2 *= inv; a3 *= inv;
    a4 *= inv; a5 *= inv; a6 *= inv; a7 *= inv;
    float* po = out + (long long)node * 384 + col_off + s16 * 8;
    *(f32x4*)po = (f32x4){a0, a1, a2, a3};
    *(f32x4*)(po + 4) = (f32x4){a4, a5, a6, a7};
}

extern "C" void kernel_launch(void* const* d_in, const int* in_sizes, int n_in,
                              void* d_out, int out_size, void* d_ws, size_t ws_size,
                              hipStream_t stream) {
    const float* x0        = (const float*)d_in[0];
    const int*   edges_raw = (const int*)d_in[1];
    const int*   ne_raw    = (const int*)d_in[2];
    const int*   mask      = (const int*)d_in[3];
    const float* W1        = (const float*)d_in[4];
    const float* b1        = (const float*)d_in[5];
    const float* W2        = (const float*)d_in[6];
    const float* b2        = (const float*)d_in[7];
    float* out = (float*)d_out;
    char* ws = (char*)d_ws;

    unsigned char*  y1   = (unsigned char*)ws;                    // B*N*F fp8 = 4 MB
    unsigned char*  y2   = (unsigned char*)(ws + 4194304);        // B*N*F fp8 = 4 MB
    unsigned short* wf   = (unsigned short*)(ws + 8388608);       // 2*128*128 = 64 KB
    int* flags           = (int*)(ws + 8454144);                  // 2 x int32
    int* sid2            = (int*)(ws + 8519680);                  // B*N*K     = 2 MB

    wprep<<<17, 256, 0, stream>>>(W1, W2, edges_raw, ne_raw, wf, flags);
    // round 1: dense node transform (+ x0 copy + sid2 pack)
    node_kernel<<<512, 256, 0, stream>>>(x0, edges_raw, ne_raw, mask,
                                         flags, wf, b1, y1, out, sid2);
    // fused: aggregate y1 -> x1 (out[:,128:256] + LDS) -> transform -> y2
    aggnode_kernel<<<512, 256, 0, stream>>>(y1, sid2, wf + 16384, b2, out, y2);
    // final aggregation
    agg_kernel<<<2048, 256, 0, stream>>>(y2, sid2, out, 256);
}